// Round 3
// baseline (844.591 us; speedup 1.0000x reference)
//
#include <hip/hip_runtime.h>
#include <hip/hip_bf16.h>

#define N_NODES   100000
#define N_EDGES   1250000
#define N_GRAPHS  512
#define HIDDEN    64
#define F_IN      3
#define N_CLASSES 5

// ---- geometry ----
#define DEG_V4    (N_EDGES / 4)                 // 312500 int4 loads of dst
#define DEG_BLKS  ((DEG_V4 + 255) / 256)        // 1221
#define CNT_BLKS  ((N_NODES + 255) / 256)       // 391  (gcnt histogram blocks)
#define AGG_BLKS  ((N_EDGES + 255) / 256)       // 4883
#define PCH       256                           // pool2 edge chunks
#define PE        ((N_EDGES + PCH - 1) / PCH)   // 4883 edges per chunk
#define PN        ((N_NODES + PCH - 1) / PCH)   // 391 nodes per chunk (self terms)
#define PREP      4                             // gsum replicas (spread flush atomics)

// bf16 helpers (RNE; inputs are finite)
__device__ __forceinline__ unsigned short f2bf(float f) {
    unsigned u = __float_as_uint(f);
    u += 0x7FFF + ((u >> 16) & 1);
    return (unsigned short)(u >> 16);
}

// ---------------------------------------------------------------------------
// k_deg: edge-parallel degree histogram (atomicAdd over dst), plus two aux
// roles in extra blocks: head fold (Wc = W2@Wl, bc = b2@Wl+bl) and the
// per-graph node-count histogram gcnt.
__global__ void __launch_bounds__(256) k_deg(
        const int4* __restrict__ dst4, const int* __restrict__ batch,
        const float* __restrict__ W2, const float* __restrict__ Wl,
        const float* __restrict__ b2, const float* __restrict__ bl,
        int* __restrict__ deg, int* __restrict__ gcnt,
        float* __restrict__ Wc, float* __restrict__ bc) {
    int b = blockIdx.x, tid = threadIdx.x;
    if (b < DEG_BLKS) {
        int t = b * 256 + tid;
        if (t < DEG_V4) {
            int4 d = dst4[t];
            atomicAdd(&deg[d.x], 1);
            atomicAdd(&deg[d.y], 1);
            atomicAdd(&deg[d.z], 1);
            atomicAdd(&deg[d.w], 1);
        }
        return;
    }
    if (b == DEG_BLKS) {                       // head fold
        for (int t = tid; t < HIDDEN * N_CLASSES + N_CLASSES; t += 256) {
            if (t < HIDDEN * N_CLASSES) {
                int k = t / N_CLASSES, c = t % N_CLASSES;
                float acc = 0.0f;
#pragma unroll
                for (int j = 0; j < HIDDEN; j++)
                    acc = fmaf(W2[k * HIDDEN + j], Wl[j * N_CLASSES + c], acc);
                Wc[t] = acc;
            } else {
                int c = t - HIDDEN * N_CLASSES;
                float acc = bl[c];
#pragma unroll
                for (int j = 0; j < HIDDEN; j++)
                    acc = fmaf(b2[j], Wl[j * N_CLASSES + c], acc);
                bc[c] = acc;
            }
        }
        return;
    }
    int n = (b - DEG_BLKS - 1) * 256 + tid;    // gcnt histogram
    if (n < N_NODES) atomicAdd(&gcnt[batch[n]], 1);
}

// ---------------------------------------------------------------------------
// k_node: per-node dis = rsqrt(deg+1) and packed bf16 xs4 = x * dis.
__global__ void __launch_bounds__(256) k_node(
        const int* __restrict__ deg, const float* __restrict__ x,
        float* __restrict__ dis, uint2* __restrict__ xs4) {
    int n = blockIdx.x * 256 + threadIdx.x;
    if (n >= N_NODES) return;
    float dv = rsqrtf((float)deg[n] + 1.0f);
    dis[n] = dv;
    float x0 = x[n * 3 + 0], x1 = x[n * 3 + 1], x2 = x[n * 3 + 2];
    xs4[n] = make_uint2((unsigned)f2bf(x0 * dv) | ((unsigned)f2bf(x1 * dv) << 16),
                        (unsigned)f2bf(x2 * dv));
}

// ---------------------------------------------------------------------------
// k_agg1: edge-parallel layer-1 aggregation. One edge per thread: gather
// xs4[src] (8B, L2-resident), 3 global f32 atomicAdds into agg4[dst].
__global__ void __launch_bounds__(256) k_agg1(
        const int* __restrict__ src, const int* __restrict__ dst,
        const uint2* __restrict__ xs4, float* __restrict__ agg) {
    int e = blockIdx.x * 256 + threadIdx.x;
    if (e >= N_EDGES) return;
    int s = src[e], d = dst[e];
    uint2 u = xs4[s];
    float f0 = __uint_as_float(u.x << 16);
    float f1 = __uint_as_float(u.x & 0xFFFF0000u);
    float f2 = __uint_as_float(u.y << 16);
    float* ap = agg + (size_t)d * 4;
    atomicAdd(ap + 0, f0);
    atomicAdd(ap + 1, f1);
    atomicAdd(ap + 2, f2);
}

// ---------------------------------------------------------------------------
// k_l1: node-parallel layer-1 finish. 4 nodes/wave, 16 lanes/node; lane j
// computes channels 4j..4j+3 of relu((agg+self)*dn @ W1 + b1)*dn, rowmax via
// 16-lane butterfly, int8 quantize, 1-dword/lane coalesced store.
// NOTE: the quantized row q[n] encodes relu(h1[n]) * dis[n] — one factor of
// dis is INSIDE the quantization. Layer-2 terms must account for exactly one
// more dis factor per side (see k_pool2).
__global__ void __launch_bounds__(256) k_l1(
        const float4* __restrict__ agg4, const uint2* __restrict__ xs4,
        const float* __restrict__ dis,
        const float* __restrict__ W1, const float* __restrict__ b1,
        unsigned* __restrict__ h1q32, float* __restrict__ hscale) {
    int w = threadIdx.x >> 6, lane = threadIdx.x & 63;
    int q4 = lane >> 4;
    int j = lane & 15;
    int node = blockIdx.x * 16 + w * 4 + q4;   // 6250*16 = 100000 exact
    float4 ag = agg4[node];
    uint2 un = xs4[node];
    float dn = dis[node];
    float a0 = dn * (ag.x + __uint_as_float(un.x << 16));
    float a1 = dn * (ag.y + __uint_as_float(un.x & 0xFFFF0000u));
    float a2 = dn * (ag.z + __uint_as_float(un.y << 16));
    float v[4];
#pragma unroll
    for (int i = 0; i < 4; i++) {
        int c = 4 * j + i;
        float t = a0 * W1[c] + a1 * W1[HIDDEN + c] + a2 * W1[2 * HIDDEN + c] + b1[c];
        v[i] = fmaxf(t, 0.0f) * dn;
    }
    float m = fmaxf(fmaxf(v[0], v[1]), fmaxf(v[2], v[3]));
#pragma unroll
    for (int off = 1; off < 16; off <<= 1) m = fmaxf(m, __shfl_xor(m, off));
    float inv = (m > 0.0f) ? 255.0f / m : 0.0f;
    unsigned packed = 0;
#pragma unroll
    for (int i = 0; i < 4; i++) {
        unsigned qv = (unsigned)(int)(v[i] * inv + 0.5f);   // 0..255
        packed |= qv << (8 * i);
    }
    h1q32[node * 16 + j] = packed;             // byte m of row == channel m
    if (j == 0) hscale[node] = m * (1.0f / 255.0f);
}

// ---------------------------------------------------------------------------
// k_pool2: layer-2 aggregation + mean-pool, edge-parallel, NO per-node output.
// q[s]*hscale[s] ~= relu(h1[s])*dis[s], so:
//   edge term: pooled[g] += q[s]*hscale[s]*dis[d]      (= h1*dis_s*dis_d)
//   self term: pooled[g] += q[n]*hscale[n]*dis[n]      (= h1*dis_n^2)
// (R2 bug was hscale[n]*dis[n]^2 on the self term -> relu*dis^3, absmax 4e-3.)
// Per-graph accumulators in LDS: gacc[32 channels][512 graphs] = 64KB,
// channel-halved across block pairs; 1024 thr (2 blocks/CU).
__global__ void __launch_bounds__(1024) k_pool2(
        const int* __restrict__ src, const int* __restrict__ dst,
        const int* __restrict__ batch, const float* __restrict__ dis,
        const float* __restrict__ hscale, const unsigned char* __restrict__ Hq,
        float* __restrict__ gsum) {
    __shared__ float gacc[32 * N_GRAPHS];
    int b = blockIdx.x;
    int chunk = b >> 1, half = b & 1;
    int tid = threadIdx.x;
    for (int i = tid; i < 32 * N_GRAPHS; i += 1024) gacc[i] = 0.0f;
    __syncthreads();
    int grp = tid >> 2;                        // 0..255: edge slot per iteration
    int q = tid & 3;                           // byte-octet within channel half
    // edge terms
    int e0 = chunk * PE;
    int eend = min(e0 + PE, N_EDGES);
    for (int e = e0 + grp; e < eend; e += 256) {
        int s = src[e], d = dst[e];
        int g = batch[d];
        float sc = hscale[s] * dis[d];
        uint2 u = *(const uint2*)(Hq + ((size_t)s << 6) + (half << 5) + (q << 3));
        int cl = q << 3;
#pragma unroll
        for (int i = 0; i < 4; i++)
            atomicAdd(&gacc[(cl + i) * N_GRAPHS + g],
                      (float)((u.x >> (8 * i)) & 0xFF) * sc);
#pragma unroll
        for (int i = 0; i < 4; i++)
            atomicAdd(&gacc[(cl + 4 + i) * N_GRAPHS + g],
                      (float)((u.y >> (8 * i)) & 0xFF) * sc);
    }
    // self terms: q[n]*hscale[n]*dis[n]  (ONE dis factor; the other is in q)
    int n0 = chunk * PN;
    int nend = min(n0 + PN, N_NODES);
    for (int n = n0 + grp; n < nend; n += 256) {
        int g = batch[n];
        float sc = hscale[n] * dis[n];
        uint2 u = *(const uint2*)(Hq + ((size_t)n << 6) + (half << 5) + (q << 3));
        int cl = q << 3;
#pragma unroll
        for (int i = 0; i < 4; i++)
            atomicAdd(&gacc[(cl + i) * N_GRAPHS + g],
                      (float)((u.x >> (8 * i)) & 0xFF) * sc);
#pragma unroll
        for (int i = 0; i < 4; i++)
            atomicAdd(&gacc[(cl + 4 + i) * N_GRAPHS + g],
                      (float)((u.y >> (8 * i)) & 0xFF) * sc);
    }
    __syncthreads();
    // flush: gsum layout [PREP][64 channels][512 graphs]; coalesced atomics
    float* gs = gsum + (size_t)(chunk & (PREP - 1)) * (HIDDEN * N_GRAPHS);
    for (int i = tid; i < 32 * N_GRAPHS; i += 1024) {
        int cl = i >> 9, g = i & (N_GRAPHS - 1);
        atomicAdd(&gs[(half * 32 + cl) * N_GRAPHS + g], gacc[i]);
    }
}

// ---------------------------------------------------------------------------
// k_head: block per graph (64 thr). gl[c] = sum of PREP replicas of pooled
// channel c; out[g,c] = dot(gl, Wc[:,c]) / max(cnt,1) + bc[c].
__global__ void __launch_bounds__(64) k_head(
        const float* __restrict__ gsum, const int* __restrict__ gcnt,
        const float* __restrict__ Wc, const float* __restrict__ bc,
        float* __restrict__ out) {
    __shared__ float gl[HIDDEN];
    int g = blockIdx.x, t = threadIdx.x;
    float s = 0.0f;
#pragma unroll
    for (int r = 0; r < PREP; r++)
        s += gsum[((size_t)r * HIDDEN + t) * N_GRAPHS + g];
    gl[t] = s;
    __syncthreads();
    if (t < N_CLASSES) {
        float cntf = fmaxf((float)gcnt[g], 1.0f);
        float dot = 0.0f;
#pragma unroll
        for (int k = 0; k < HIDDEN; k++)
            dot = fmaf(gl[k], Wc[k * N_CLASSES + t], dot);
        out[g * N_CLASSES + t] = dot / cntf + bc[t];
    }
}

// ---------------------------------------------------------------------------
extern "C" void kernel_launch(void* const* d_in, const int* in_sizes, int n_in,
                              void* d_out, int out_size, void* d_ws, size_t ws_size,
                              hipStream_t stream) {
    const float* x     = (const float*)d_in[0];
    const int*   ei    = (const int*)  d_in[1];   // [2, N_EDGES] flat: src then dst
    const int*   batch = (const int*)  d_in[2];
    const float* W1    = (const float*)d_in[3];
    const float* b1    = (const float*)d_in[4];
    const float* W2    = (const float*)d_in[5];
    const float* b2    = (const float*)d_in[6];
    const float* Wl    = (const float*)d_in[7];
    const float* bl    = (const float*)d_in[8];
    float* out = (float*)d_out;

    const int* src = ei;
    const int* dst = ei + N_EDGES;

    // workspace layout (4B words). Zeroed region first (one memset):
    //   deg[100000] | agg[100000*4] (16B-aligned) | gsum[PREP*64*512] | gcnt[512]
    // then un-zeroed: dis | hscale | xs4 (8B-aligned) | h1q | Wc | bc
    int*   deg    = (int*)d_ws;                               // 100000
    float* agg    = (float*)(deg + N_NODES);                  // 400000 (16B ok)
    float* gsum   = agg + (size_t)N_NODES * 4;                // PREP*64*512
    int*   gcnt   = (int*)(gsum + PREP * HIDDEN * N_GRAPHS);  // 512
    float* dis    = (float*)(gcnt + N_GRAPHS);                // 100000
    float* hscale = dis + N_NODES;                            // 100000
    uint2* xs4    = (uint2*)(hscale + N_NODES);               // 100000 uint2
    unsigned* h1q32 = (unsigned*)(xs4 + N_NODES);             // 16N words
    float* Wc     = (float*)(h1q32 + (size_t)N_NODES * 16);   // 64*5
    float* bc     = Wc + HIDDEN * N_CLASSES;                  // 5

    const size_t zero_words = (size_t)N_NODES + (size_t)N_NODES * 4 +
                              (size_t)PREP * HIDDEN * N_GRAPHS + N_GRAPHS;
    hipMemsetAsync(deg, 0, zero_words * sizeof(int), stream);

    // degree + gcnt + head fold
    k_deg<<<DEG_BLKS + 1 + CNT_BLKS, 256, 0, stream>>>(
        (const int4*)dst, batch, W2, Wl, b2, bl, deg, gcnt, Wc, bc);
    // per-node scale + packed features
    k_node<<<CNT_BLKS, 256, 0, stream>>>(deg, x, dis, xs4);
    // layer-1 aggregation (edge-parallel atomics)
    k_agg1<<<AGG_BLKS, 256, 0, stream>>>(src, dst, xs4, agg);
    // layer-1 finish + int8 quantize
    k_l1<<<N_NODES / 16, 256, 0, stream>>>((const float4*)agg, xs4, dis, W1, b1,
                                           h1q32, hscale);
    // layer-2 aggregation + pool (edge-parallel, per-graph LDS accumulators)
    k_pool2<<<PCH * 2, 1024, 0, stream>>>(src, dst, batch, dis, hscale,
                                          (const unsigned char*)h1q32, gsum);
    // head
    k_head<<<N_GRAPHS, HIDDEN, 0, stream>>>(gsum, gcnt, Wc, bc, out);
}

// Round 4
// 223.447 us; speedup vs baseline: 3.7798x; 3.7798x over previous
//
#include <hip/hip_runtime.h>
#include <hip/hip_bf16.h>

#define N_NODES   100000
#define N_EDGES   1250000
#define N_GRAPHS  512
#define HIDDEN    64
#define F_IN      3
#define N_CLASSES 5

#define CAPN      64                            // static per-node CSR capacity
#define NREP      8                             // gsum replicas (legacy-proven)

#define DEG_V4    (N_EDGES / 4)                 // 312500 int4 groups
#define EB4       ((DEG_V4 + 255) / 256)        // 1221 edge blocks
#define GST_BLKS  ((N_NODES + 255) / 256)       // 391 gstart / node blocks

// bf16 helpers (RNE; inputs are finite)
__device__ __forceinline__ unsigned short f2bf(float f) {
    unsigned u = __float_as_uint(f);
    u += 0x7FFF + ((u >> 16) & 1);
    return (unsigned short)(u >> 16);
}

// ---------------------------------------------------------------------------
// k_scat2: ONE-pass CSR build. Per edge: claim slot via returning atomicAdd
// on deg[dst], store src into the statically-padded row d*CAPN+lp. Replaces
// legacy's k_scat(ebuf scatter) + k_bktfill(re-read + re-scatter) pair.
// Extra blocks: head fold (Wc = W2@Wl, bc = b2@Wl+bl) and gstart boundaries
// from the sorted batch vector (both verbatim from the 161us legacy kernel).
__global__ void __launch_bounds__(256) k_scat2(
        const int4* __restrict__ src4, const int4* __restrict__ dst4,
        const int* __restrict__ batch,
        const float* __restrict__ W2, const float* __restrict__ Wl,
        const float* __restrict__ b2, const float* __restrict__ bl,
        int* __restrict__ deg, int* __restrict__ elist,
        float* __restrict__ Wc, float* __restrict__ bc,
        int* __restrict__ gstart) {
    int b = blockIdx.x, tid = threadIdx.x;
    if (b < EB4) {
        int t = b * 256 + tid;
        if (t < DEG_V4) {
            int4 s4 = src4[t];
            int4 d4 = dst4[t];
            int lp;
            lp = atomicAdd(&deg[d4.x], 1);
            if (lp < CAPN) elist[d4.x * CAPN + lp] = s4.x;
            lp = atomicAdd(&deg[d4.y], 1);
            if (lp < CAPN) elist[d4.y * CAPN + lp] = s4.y;
            lp = atomicAdd(&deg[d4.z], 1);
            if (lp < CAPN) elist[d4.z * CAPN + lp] = s4.z;
            lp = atomicAdd(&deg[d4.w], 1);
            if (lp < CAPN) elist[d4.w * CAPN + lp] = s4.w;
        }
        return;
    }
    if (b == EB4) {                            // head fold
        for (int t = tid; t < HIDDEN * N_CLASSES + N_CLASSES; t += 256) {
            if (t < HIDDEN * N_CLASSES) {
                int k = t / N_CLASSES, c = t % N_CLASSES;
                float acc = 0.0f;
#pragma unroll
                for (int j = 0; j < HIDDEN; j++)
                    acc = fmaf(W2[k * HIDDEN + j], Wl[j * N_CLASSES + c], acc);
                Wc[t] = acc;
            } else {
                int c = t - HIDDEN * N_CLASSES;
                float acc = bl[c];
#pragma unroll
                for (int j = 0; j < HIDDEN; j++)
                    acc = fmaf(b2[j], Wl[j * N_CLASSES + c], acc);
                bc[c] = acc;
            }
        }
        return;
    }
    int n = (b - EB4 - 1) * 256 + tid;         // gstart from sorted batch
    if (n >= N_NODES) return;
    if (n == 0) {
        for (int g = 0; g <= batch[0]; g++) gstart[g] = 0;
    } else {
        int b0 = batch[n - 1], b1 = batch[n];
        for (int g = b0 + 1; g <= b1; g++) gstart[g] = n;
    }
    if (n == N_NODES - 1) {
        for (int g = batch[n] + 1; g <= N_GRAPHS; g++) gstart[g] = N_NODES;
    }
}

// ---------------------------------------------------------------------------
// k_node: per-node dis = rsqrt(deg+1) and packed bf16 xs4 = x * dis.
// (Needs completed deg, hence its own dispatch; ~100K threads, trivial.)
__global__ void __launch_bounds__(256) k_node(
        const int* __restrict__ deg, const float* __restrict__ x,
        float* __restrict__ dis, uint2* __restrict__ xs4) {
    int n = blockIdx.x * 256 + threadIdx.x;
    if (n >= N_NODES) return;
    float dv = rsqrtf((float)min(deg[n], CAPN) + 1.0f);
    dis[n] = dv;
    float x0 = x[n * 3 + 0], x1 = x[n * 3 + 1], x2 = x[n * 3 + 2];
    xs4[n] = make_uint2((unsigned)f2bf(x0 * dv) | ((unsigned)f2bf(x1 * dv) << 16),
                        (unsigned)f2bf(x2 * dv));
}

// ---------------------------------------------------------------------------
// fused layer-1 (legacy-proven): FOUR nodes per wave (16 lanes each). Lane-
// parallel 3-channel gather, 4-stage quarter-butterfly, each lane computes 4
// channels of relu(aggx@W1+b1)*dis, rowmax + local byte-pack -> coalesced
// 1-dword/lane store. Only change vs 161us legacy: rp[node] -> node*CAPN.
__global__ void __launch_bounds__(256) k_l1fused(
        const int* __restrict__ degA, const int* __restrict__ elist,
        const float* __restrict__ dis, const uint2* __restrict__ xs4,
        const float* __restrict__ W1, const float* __restrict__ b1,
        unsigned* __restrict__ h1q32, float* __restrict__ hscale) {
    int w = threadIdx.x >> 6, lane = threadIdx.x & 63;
    int q4 = lane >> 4;                   // which of 4 nodes in this wave
    int j  = lane & 15;                   // lane within node (16-wide)
    int node = blockIdx.x * 16 + w * 4 + q4;   // 6250*16 = 100000 exact
    int start = node * CAPN;
    int dg = min(degA[node], CAPN);
    float a0 = 0.f, a1 = 0.f, a2 = 0.f;
    for (int k = 0; k < dg; k += 16) {    // divergent bound across quarters: ok
        int idx = k + j;
        bool act = idx < dg;
        int s = elist[start + (act ? idx : 0)];
        uint2 u = xs4[s];
        float msk = act ? 1.0f : 0.0f;
        a0 = fmaf(__uint_as_float(u.x << 16), msk, a0);
        a1 = fmaf(__uint_as_float(u.x & 0xFFFF0000u), msk, a1);
        a2 = fmaf(__uint_as_float(u.y << 16), msk, a2);
    }
#pragma unroll
    for (int off = 1; off < 16; off <<= 1) {   // butterfly within 16-lane quarter
        a0 += __shfl_xor(a0, off);
        a1 += __shfl_xor(a1, off);
        a2 += __shfl_xor(a2, off);
    }
    uint2 un = xs4[node];
    float dn = dis[node];
    a0 = dn * (a0 + __uint_as_float(un.x << 16));
    a1 = dn * (a1 + __uint_as_float(un.x & 0xFFFF0000u));
    a2 = dn * (a2 + __uint_as_float(un.y << 16));
    // each lane: channels 4j .. 4j+3
    float v[4];
#pragma unroll
    for (int i = 0; i < 4; i++) {
        int c = 4 * j + i;
        float t = a0 * W1[c] + a1 * W1[HIDDEN + c] + a2 * W1[2 * HIDDEN + c] + b1[c];
        v[i] = fmaxf(t, 0.0f) * dn;
    }
    float m = fmaxf(fmaxf(v[0], v[1]), fmaxf(v[2], v[3]));
#pragma unroll
    for (int off = 1; off < 16; off <<= 1) m = fmaxf(m, __shfl_xor(m, off));
    float inv = (m > 0.0f) ? 255.0f / m : 0.0f;
    unsigned packed = 0;
#pragma unroll
    for (int i = 0; i < 4; i++) {
        unsigned qv = (unsigned)(int)(v[i] * inv + 0.5f);   // 0..255
        packed |= qv << (8 * i);
    }
    h1q32[node * 16 + j] = packed;        // 16 consecutive lanes -> 64B row
    if (j == 0) hscale[node] = m * (1.0f / 255.0f);
}

// ---------------------------------------------------------------------------
// fused 64-channel gather + mean-pool accumulate (legacy-proven). TWO nodes
// per wave (32 lanes each: 4 edges in flight x 8 uint2-octets). Register
// accumulation + 2 xor stages; block's 8 node-rows merged by graph in LDS,
// flushed to one of NREP gsum replicas. Only change: rp[node] -> node*CAPN.
__global__ void __launch_bounds__(256) k_gatherpool(
        const int* __restrict__ degA, const int* __restrict__ elist,
        const float* __restrict__ dis,
        const unsigned char* __restrict__ Hq,
        const float* __restrict__ Hs,
        const int* __restrict__ batch,
        float* __restrict__ gsum8) {
    __shared__ float acc_s[8][HIDDEN];
    __shared__ int gid[8];
    int w = threadIdx.x >> 6, lane = threadIdx.x & 63;
    int half = lane >> 5;                       // which of 2 nodes in this wave
    int l32 = lane & 31;
    int node = blockIdx.x * 8 + w * 2 + half;   // 12500*8 = 100000 exact
    int start = node * CAPN;
    int dg = min(degA[node], CAPN);
    int eg = l32 >> 3;       // which of 4 concurrent edges
    int ch = lane & 7;       // which byte-octet (uint2) of the row
    float acc[8] = {0.f, 0.f, 0.f, 0.f, 0.f, 0.f, 0.f, 0.f};
    for (int k = 0; k < dg; k += 4) {     // divergent bound across halves: ok
        int idx = k + eg;
        bool act = idx < dg;
        int s = elist[start + (act ? idx : 0)];
        float sc = act ? Hs[s] : 0.0f;
        uint2 u = *(const uint2*)(Hq + ((size_t)s << 6) + (ch << 3));
#pragma unroll
        for (int i = 0; i < 4; i++)
            acc[i] = fmaf((float)((u.x >> (8 * i)) & 0xFF), sc, acc[i]);
#pragma unroll
        for (int i = 0; i < 4; i++)
            acc[4 + i] = fmaf((float)((u.y >> (8 * i)) & 0xFF), sc, acc[4 + i]);
    }
#pragma unroll
    for (int i = 0; i < 8; i++) {         // reduce 4 edge-groups (within half)
        acc[i] += __shfl_xor(acc[i], 8);
        acc[i] += __shfl_xor(acc[i], 16);
    }
    if (l32 == 0) gid[w * 2 + half] = batch[node];
    if (l32 < 8) {                        // eg==0 lanes hold octet l32
        float dn = dis[node];
        float scN = Hs[node];
        uint2 u = *(const uint2*)(Hq + ((size_t)node << 6) + (l32 << 3));
        float o[8];
#pragma unroll
        for (int i = 0; i < 4; i++)
            o[i] = dn * fmaf((float)((u.x >> (8 * i)) & 0xFF), scN, acc[i]);
#pragma unroll
        for (int i = 0; i < 4; i++)
            o[4 + i] = dn * fmaf((float)((u.y >> (8 * i)) & 0xFF), scN, acc[4 + i]);
        float* dst = &acc_s[w * 2 + half][l32 * 8];
        *(float4*)(dst)     = make_float4(o[0], o[1], o[2], o[3]);
        *(float4*)(dst + 4) = make_float4(o[4], o[5], o[6], o[7]);
    }
    __syncthreads();
    float* gs = gsum8 + (size_t)(blockIdx.x & (NREP - 1)) * (N_GRAPHS * HIDDEN);
    if (threadIdx.x < HIDDEN) {
        int t = threadIdx.x;
#pragma unroll
        for (int wv = 0; wv < 8; wv++) {
            int gw = gid[wv];
            bool first = true;
#pragma unroll
            for (int u = 0; u < wv; u++)
                if (gid[u] == gw) first = false;
            if (first) {
                float s = acc_s[wv][t];
#pragma unroll
                for (int u2 = wv + 1; u2 < 8; u2++)
                    if (gid[u2] == gw) s += acc_s[u2][t];
                atomicAdd(&gs[gw * HIDDEN + t], s);
            }
        }
    }
}

// head: one block (64 thr) per graph; sum the NREP gsum replicas, then
// out[g,c] = (gl @ Wc[:,c]) / max(cnt,1) + bc[c]   (legacy-proven)
__global__ void __launch_bounds__(64) k_head(
        const float* __restrict__ gsum8, const int* __restrict__ gstart,
        const float* __restrict__ Wc, const float* __restrict__ bc,
        float* __restrict__ out) {
    __shared__ float gl[HIDDEN];
    int g = blockIdx.x, t = threadIdx.x;
    float s = 0.0f;
#pragma unroll
    for (int r = 0; r < NREP; r++)
        s += gsum8[(size_t)r * (N_GRAPHS * HIDDEN) + g * HIDDEN + t];
    gl[t] = s;
    __syncthreads();
    if (t < N_CLASSES) {
        float cntf = fmaxf((float)(gstart[g + 1] - gstart[g]), 1.0f);
        float dot = 0.0f;
#pragma unroll
        for (int k = 0; k < HIDDEN; k++)
            dot = fmaf(gl[k], Wc[k * N_CLASSES + t], dot);
        out[g * N_CLASSES + t] = dot / cntf + bc[t];
    }
}

// ---------------------------------------------------------------------------
extern "C" void kernel_launch(void* const* d_in, const int* in_sizes, int n_in,
                              void* d_out, int out_size, void* d_ws, size_t ws_size,
                              hipStream_t stream) {
    const float* x     = (const float*)d_in[0];
    const int*   ei    = (const int*)  d_in[1];   // [2, N_EDGES] flat: src then dst
    const int*   batch = (const int*)  d_in[2];
    const float* W1    = (const float*)d_in[3];
    const float* b1    = (const float*)d_in[4];
    const float* W2    = (const float*)d_in[5];
    const float* b2    = (const float*)d_in[6];
    const float* Wl    = (const float*)d_in[7];
    const float* bl    = (const float*)d_in[8];
    float* out = (float*)d_out;

    const int* src = ei;
    const int* dst = ei + N_EDGES;

    // workspace layout (4B words). Zeroed region first (one memset):
    //   deg[100000] | gsum8[NREP*512*64]
    // then un-zeroed: elist | dis | hscale | xs4 (8B-aligned) | h1q |
    //   gstart(516) | Wc | bc
    int*   deg    = (int*)d_ws;                               // 100000
    float* gsum8  = (float*)(deg + N_NODES);                  // NREP*512*64
    int*   elist  = (int*)(gsum8 + NREP * N_GRAPHS * HIDDEN); // N*CAPN
    float* dis    = (float*)(elist + (size_t)N_NODES * CAPN); // 100000
    float* hscale = dis + N_NODES;                            // 100000
    uint2* xs4    = (uint2*)(hscale + N_NODES);               // 100000 uint2
    unsigned* h1q32 = (unsigned*)(xs4 + N_NODES);             // 16N words
    int*   gstart = (int*)(h1q32 + (size_t)N_NODES * 16);     // N_GRAPHS+1 pad 516
    float* Wc     = (float*)(gstart + 516);                   // 64*5
    float* bc     = Wc + HIDDEN * N_CLASSES;                  // 5

    const size_t zero_words = (size_t)N_NODES + (size_t)NREP * N_GRAPHS * HIDDEN;
    hipMemsetAsync(deg, 0, zero_words * sizeof(int), stream);

    // one-pass CSR build (+ head fold + gstart in extra blocks)
    k_scat2<<<EB4 + 1 + GST_BLKS, 256, 0, stream>>>(
        (const int4*)src, (const int4*)dst, batch, W2, Wl, b2, bl,
        deg, elist, Wc, bc, gstart);
    // per-node scale + packed bf16 features (needs completed deg)
    k_node<<<GST_BLKS, 256, 0, stream>>>(deg, x, dis, xs4);
    // fused layer 1 (4 nodes/wave: 16-lane gather + W1 + local-pack quantize)
    k_l1fused<<<N_NODES / 16, 256, 0, stream>>>(deg, elist, dis, xs4, W1, b1,
                                                h1q32, hscale);
    // layer 2 aggregation fused with mean-pool accumulation (2 nodes/wave)
    k_gatherpool<<<N_NODES / 8, 256, 0, stream>>>(deg, elist, dis,
                                                  (const unsigned char*)h1q32,
                                                  hscale, batch, gsum8);
    // folded head (block per graph; sums the NREP replicas)
    k_head<<<N_GRAPHS, HIDDEN, 0, stream>>>(gsum8, gstart, Wc, bc, out);
}

// Round 5
// 172.361 us; speedup vs baseline: 4.9001x; 1.2964x over previous
//
#include <hip/hip_runtime.h>
#include <hip/hip_bf16.h>

#define N_NODES   100000
#define N_EDGES   1250000
#define N_GRAPHS  512
#define HIDDEN    64
#define F_IN      3
#define N_CLASSES 5

// bucket sort parameters (legacy-proven: 161us)
#define BKT_SHIFT 8
#define BKT_NODES 256                                      // nodes per bucket
#define N_BKT     ((N_NODES + BKT_NODES - 1) / BKT_NODES)  // 391
#define CAP       4096                                     // fixed bucket capacity
#define EBLK      512                                      // edge blocks in k_scat
#define ECHUNK    ((N_EDGES + EBLK - 1) / EBLK)            // 2442
#define SCT       512                                      // k_scat threads
#define NREP      8                                        // gsum replicas

// bf16 helpers (RNE; inputs are finite)
__device__ __forceinline__ unsigned short f2bf(float f) {
    unsigned u = __float_as_uint(f);
    u += 0x7FFF + ((u >> 16) & 1);
    return (unsigned short)(u >> 16);
}

// ---------------------------------------------------------------------------
// k_scat: merged hist + bucket-base claim + scatter (+ head fold, gstart in
// extra blocks). Edges are cached in LDS during the hist pass, so src/dst are
// read from global exactly once. NO per-edge global atomics (R4 lesson: those
// cost ~107us in cross-XCD line bounce; per-block run claims avoid it).
__global__ void k_scat(const int* __restrict__ src, const int* __restrict__ dst,
                       const float* __restrict__ W2, const float* __restrict__ Wl,
                       const float* __restrict__ b2, const float* __restrict__ bl,
                       const int* __restrict__ batch,
                       int* __restrict__ gcur, int* __restrict__ ebuf,
                       float* __restrict__ Wc, float* __restrict__ bc,
                       int* __restrict__ gstart) {
    int b = blockIdx.x;
    int tid = threadIdx.x;
    if (b >= EBLK) {
        int bb = b - EBLK;
        if (bb == 0) {                      // head fold: Wc = W2@Wl, bc = b2@Wl+bl
            for (int t = tid; t < HIDDEN * N_CLASSES + N_CLASSES; t += SCT) {
                if (t < HIDDEN * N_CLASSES) {
                    int k = t / N_CLASSES, c = t % N_CLASSES;
                    float acc = 0.0f;
#pragma unroll
                    for (int j = 0; j < HIDDEN; j++)
                        acc = fmaf(W2[k * HIDDEN + j], Wl[j * N_CLASSES + c], acc);
                    Wc[t] = acc;
                } else {
                    int c = t - HIDDEN * N_CLASSES;
                    float acc = bl[c];
#pragma unroll
                    for (int j = 0; j < HIDDEN; j++)
                        acc = fmaf(b2[j], Wl[j * N_CLASSES + c], acc);
                    bc[c] = acc;
                }
            }
            return;
        }
        int n = (bb - 1) * SCT + tid;       // gstart from sorted batch
        if (n >= N_NODES) return;
        if (n == 0) {
            for (int g = 0; g <= batch[0]; g++) gstart[g] = 0;
        } else {
            int b0 = batch[n - 1], b1 = batch[n];
            for (int g = b0 + 1; g <= b1; g++) gstart[g] = n;
        }
        if (n == N_NODES - 1) {
            for (int g = batch[n] + 1; g <= N_GRAPHS; g++) gstart[g] = N_NODES;
        }
        return;
    }
    // scatter blocks: edges cached in LDS across the two passes
    __shared__ int pk[ECHUNK];
    __shared__ unsigned short bkl[ECHUNK];
    __shared__ int h[N_BKT];
    __shared__ int cur[N_BKT];
    for (int i = tid; i < N_BKT; i += SCT) h[i] = 0;
    __syncthreads();
    int e0 = b * ECHUNK;
    int m = min(ECHUNK, N_EDGES - e0);
    for (int i = tid; i < m; i += SCT) {
        int s = src[e0 + i], d = dst[e0 + i];
        int bk = d >> BKT_SHIFT;
        pk[i] = (s << BKT_SHIFT) | (d & (BKT_NODES - 1));
        bkl[i] = (unsigned short)bk;
        atomicAdd(&h[bk], 1);
    }
    __syncthreads();
    for (int i = tid; i < N_BKT; i += SCT)
        cur[i] = atomicAdd(&gcur[i], h[i]);    // claim this block's run in bucket i
    __syncthreads();
    for (int i = tid; i < m; i += SCT) {
        int bk = bkl[i];
        int lp = atomicAdd(&cur[bk], 1);
        if (lp < CAP)                           // defensive (P~0 overflow)
            ebuf[bk * CAP + lp] = pk[i];
    }
}

// k_bktfill: per-bucket CSR build, single global pass — the bucket's edges are
// cached in LDS (<=16KB) during the degree-hist pass, then the scatter reads
// from LDS. 391 blocks x 1024 threads (2 resident blocks/CU).
__global__ void k_bktfill(const int* __restrict__ ebuf, const int* __restrict__ gcur,
                          const float* __restrict__ x,
                          int* __restrict__ rowptr, int* __restrict__ deg,
                          float* __restrict__ dis, uint2* __restrict__ xs4,
                          int* __restrict__ elist) {
    __shared__ int eb_l[CAP];
    __shared__ int cnt_l[BKT_NODES];
    __shared__ int cur_l[BKT_NODES];
    __shared__ int ps[BKT_NODES];
    int b = blockIdx.x, tid = threadIdx.x;   // 0..1023
    int n0 = b * BKT_NODES;
    int e0 = b * CAP;
    int cnt = min(gcur[b], CAP);
    if (tid < BKT_NODES) cnt_l[tid] = 0;
    __syncthreads();
    for (int i = tid; i < cnt; i += 1024) {
        int pe = ebuf[e0 + i];
        eb_l[i] = pe;
        atomicAdd(&cnt_l[pe & (BKT_NODES - 1)], 1);
    }
    __syncthreads();
    if (tid < BKT_NODES) ps[tid] = cnt_l[tid];
    __syncthreads();
    for (int off = 1; off < BKT_NODES; off <<= 1) {
        int t = 0;
        if (tid < BKT_NODES && tid >= off) t = ps[tid - off];
        __syncthreads();
        if (tid < BKT_NODES) ps[tid] += t;
        __syncthreads();
    }
    if (tid < BKT_NODES) {
        int node = n0 + tid;
        int excl = ps[tid] - cnt_l[tid];       // exclusive scan
        cur_l[tid] = excl;
        if (node < N_NODES) {
            rowptr[node] = e0 + excl;
            deg[node] = cnt_l[tid];
            float dv = rsqrtf((float)cnt_l[tid] + 1.0f);
            dis[node] = dv;
            float x0 = x[node * 3 + 0], x1 = x[node * 3 + 1], x2 = x[node * 3 + 2];
            xs4[node] = make_uint2((unsigned)f2bf(x0 * dv) |
                                   ((unsigned)f2bf(x1 * dv) << 16),
                                   (unsigned)f2bf(x2 * dv));
        }
    }
    __syncthreads();
    for (int i = tid; i < cnt; i += 1024) {
        int pe = eb_l[i];
        int pos = atomicAdd(&cur_l[pe & (BKT_NODES - 1)], 1);
        elist[e0 + pos] = ((unsigned)pe) >> BKT_SHIFT;
    }
}

// ---------------------------------------------------------------------------
// fused layer-1 (legacy-proven, unchanged): FOUR nodes per wave (16 lanes
// each). Lane-parallel 3-channel gather, 4-stage quarter-butterfly, each lane
// computes 4 channels of relu(aggx@W1+b1)*dis, local rowmax + byte-pack ->
// coalesced 1-dword/lane store.
__global__ void k_l1fused(const int* __restrict__ rp, const int* __restrict__ degA,
                          const int* __restrict__ elist,
                          const float* __restrict__ dis, const uint2* __restrict__ xs4,
                          const float* __restrict__ W1, const float* __restrict__ b1,
                          unsigned* __restrict__ h1q32, float* __restrict__ hscale) {
    int w = threadIdx.x >> 6, lane = threadIdx.x & 63;
    int q4 = lane >> 4;                   // which of 4 nodes in this wave
    int j  = lane & 15;                   // lane within node (16-wide)
    int node = blockIdx.x * 16 + w * 4 + q4;   // 6250*16 = 100000 exact
    int start = rp[node], dg = degA[node];
    float a0 = 0.f, a1 = 0.f, a2 = 0.f;
    for (int k = 0; k < dg; k += 16) {    // divergent bound across quarters: ok
        int idx = k + j;
        bool act = idx < dg;
        int s = elist[start + (act ? idx : 0)];
        uint2 u = xs4[s];
        float msk = act ? 1.0f : 0.0f;
        a0 = fmaf(__uint_as_float(u.x << 16), msk, a0);
        a1 = fmaf(__uint_as_float(u.x & 0xFFFF0000u), msk, a1);
        a2 = fmaf(__uint_as_float(u.y << 16), msk, a2);
    }
#pragma unroll
    for (int off = 1; off < 16; off <<= 1) {   // butterfly within 16-lane quarter
        a0 += __shfl_xor(a0, off);
        a1 += __shfl_xor(a1, off);
        a2 += __shfl_xor(a2, off);
    }
    uint2 un = xs4[node];
    float dn = dis[node];
    a0 = dn * (a0 + __uint_as_float(un.x << 16));
    a1 = dn * (a1 + __uint_as_float(un.x & 0xFFFF0000u));
    a2 = dn * (a2 + __uint_as_float(un.y << 16));
    // each lane: channels 4j .. 4j+3
    float v[4];
#pragma unroll
    for (int i = 0; i < 4; i++) {
        int c = 4 * j + i;
        float t = a0 * W1[c] + a1 * W1[HIDDEN + c] + a2 * W1[2 * HIDDEN + c] + b1[c];
        v[i] = fmaxf(t, 0.0f) * dn;
    }
    float m = fmaxf(fmaxf(v[0], v[1]), fmaxf(v[2], v[3]));
#pragma unroll
    for (int off = 1; off < 16; off <<= 1) m = fmaxf(m, __shfl_xor(m, off));
    float inv = (m > 0.0f) ? 255.0f / m : 0.0f;
    unsigned packed = 0;
#pragma unroll
    for (int i = 0; i < 4; i++) {
        unsigned qv = (unsigned)(int)(v[i] * inv + 0.5f);   // 0..255
        packed |= qv << (8 * i);
    }
    h1q32[node * 16 + j] = packed;        // 16 consecutive lanes -> 64B row
    if (j == 0) hscale[node] = m * (1.0f / 255.0f);
}

// ---------------------------------------------------------------------------
// fused 64-channel gather + mean-pool accumulate.
// ROUND-5 CHANGE (isolated A/B vs legacy): ONE node per wave (was 2), with
// EIGHT edges in flight (was 4) x 8 uint2-octets. Mean deg 12.5 -> serial
// gather iterations drop 3.2 -> 1.6 (theory: this loop is a ~600cy/iter
// latency chain — elist -> Hs/Hq row gather — and the kernel is chain-bound,
// VALUBusy ~2-4%). Reduction: 3 xor stages (8,16,32). Block's 4 waves stage
// 4 node-rows in LDS, 64 threads merge same-graph rows, flush to one of NREP
// gsum replicas (batch sorted -> typically 1 atomic round of 64).
__global__ void k_gatherpool(const int* __restrict__ rp, const int* __restrict__ degA,
                             const int* __restrict__ elist,
                             const float* __restrict__ dis,
                             const unsigned char* __restrict__ Hq,
                             const float* __restrict__ Hs,
                             const int* __restrict__ batch,
                             float* __restrict__ gsum8) {
    __shared__ float acc_s[4][HIDDEN];
    __shared__ int gid[4];
    int w = threadIdx.x >> 6, lane = threadIdx.x & 63;
    int node = blockIdx.x * 4 + w;              // 25000*4 = 100000 exact
    int start = rp[node], dg = degA[node];
    int eg = lane >> 3;      // which of 8 concurrent edges
    int ch = lane & 7;       // which byte-octet (uint2) of the row
    float acc[8] = {0.f, 0.f, 0.f, 0.f, 0.f, 0.f, 0.f, 0.f};
    for (int k = 0; k < dg; k += 8) {     // divergent bound across waves: ok
        int idx = k + eg;
        bool act = idx < dg;
        int s = elist[start + (act ? idx : 0)];
        float sc = act ? Hs[s] : 0.0f;
        uint2 u = *(const uint2*)(Hq + ((size_t)s << 6) + (ch << 3));
#pragma unroll
        for (int i = 0; i < 4; i++)
            acc[i] = fmaf((float)((u.x >> (8 * i)) & 0xFF), sc, acc[i]);
#pragma unroll
        for (int i = 0; i < 4; i++)
            acc[4 + i] = fmaf((float)((u.y >> (8 * i)) & 0xFF), sc, acc[4 + i]);
    }
#pragma unroll
    for (int i = 0; i < 8; i++) {         // reduce 8 edge-groups: full butterfly
        acc[i] += __shfl_xor(acc[i], 8);
        acc[i] += __shfl_xor(acc[i], 16);
        acc[i] += __shfl_xor(acc[i], 32);
    }
    if (lane == 0) gid[w] = batch[node];
    if (lane < 8) {                       // eg==0 lanes hold octet 'lane'
        float dn = dis[node];
        float scN = Hs[node];
        uint2 u = *(const uint2*)(Hq + ((size_t)node << 6) + (lane << 3));
        float o[8];
#pragma unroll
        for (int i = 0; i < 4; i++)
            o[i] = dn * fmaf((float)((u.x >> (8 * i)) & 0xFF), scN, acc[i]);
#pragma unroll
        for (int i = 0; i < 4; i++)
            o[4 + i] = dn * fmaf((float)((u.y >> (8 * i)) & 0xFF), scN, acc[4 + i]);
        float* dst = &acc_s[w][lane * 8];
        *(float4*)(dst)     = make_float4(o[0], o[1], o[2], o[3]);
        *(float4*)(dst + 4) = make_float4(o[4], o[5], o[6], o[7]);
    }
    __syncthreads();
    float* gs = gsum8 + (size_t)(blockIdx.x & (NREP - 1)) * (N_GRAPHS * HIDDEN);
    if (threadIdx.x < HIDDEN) {
        int t = threadIdx.x;
#pragma unroll
        for (int wv = 0; wv < 4; wv++) {
            int gw = gid[wv];
            bool first = true;
#pragma unroll
            for (int u = 0; u < wv; u++)
                if (gid[u] == gw) first = false;
            if (first) {
                float s = acc_s[wv][t];
#pragma unroll
                for (int u2 = wv + 1; u2 < 4; u2++)
                    if (gid[u2] == gw) s += acc_s[u2][t];
                atomicAdd(&gs[gw * HIDDEN + t], s);
            }
        }
    }
}

// head: one block (64 thr) per graph; sum the NREP gsum replicas, then
// out[g,c] = (gl @ Wc[:,c]) / max(cnt,1) + bc[c]
__global__ void k_head(const float* __restrict__ gsum8, const int* __restrict__ gstart,
                       const float* __restrict__ Wc, const float* __restrict__ bc,
                       float* __restrict__ out) {
    __shared__ float gl[HIDDEN];
    int g = blockIdx.x, t = threadIdx.x;
    float s = 0.0f;
#pragma unroll
    for (int r = 0; r < NREP; r++)
        s += gsum8[(size_t)r * (N_GRAPHS * HIDDEN) + g * HIDDEN + t];
    gl[t] = s;
    __syncthreads();
    if (t < N_CLASSES) {
        float cntf = fmaxf((float)(gstart[g + 1] - gstart[g]), 1.0f);
        float dot = 0.0f;
#pragma unroll
        for (int k = 0; k < HIDDEN; k++)
            dot = fmaf(gl[k], Wc[k * N_CLASSES + t], dot);
        out[g * N_CLASSES + t] = dot / cntf + bc[t];
    }
}

// ---------------------------------------------------------------------------
extern "C" void kernel_launch(void* const* d_in, const int* in_sizes, int n_in,
                              void* d_out, int out_size, void* d_ws, size_t ws_size,
                              hipStream_t stream) {
    const float* x     = (const float*)d_in[0];
    const int*   ei    = (const int*)  d_in[1];   // [2, N_EDGES] flat: src then dst
    const int*   batch = (const int*)  d_in[2];
    const float* W1    = (const float*)d_in[3];
    const float* b1    = (const float*)d_in[4];
    const float* W2    = (const float*)d_in[5];
    const float* b2    = (const float*)d_in[6];
    const float* Wl    = (const float*)d_in[7];
    const float* bl    = (const float*)d_in[8];
    float* out = (float*)d_out;

    const int* src = ei;
    const int* dst = ei + N_EDGES;

    // workspace layout (4B words; gcur+gsum8 adjacent so ONE memset zeros both;
    // word-offset parity keeps xs4 8B-aligned)  — identical to the 161us legacy
    int*   gcur    = (int*)d_ws;                         // 391, pad to 512
    float* gsum8   = (float*)(gcur + 512);               // NREP*512*64
    int*   ebuf    = (int*)(gsum8 + NREP * N_GRAPHS * HIDDEN); // N_BKT*CAP
    int*   elist   = ebuf + N_BKT * CAP;                 // N_BKT*CAP
    int*   rp      = elist + N_BKT * CAP;                // N
    int*   deg     = rp + N_NODES;                       // N
    float* dis     = (float*)(deg + N_NODES);            // N
    float* hscale  = dis + N_NODES;                      // N
    uint2* xs4     = (uint2*)(hscale + N_NODES);         // N uint2 (8B-aligned)
    unsigned* h1q32 = (unsigned*)(xs4 + N_NODES);        // 16N words (uint8 rows)
    int*   gstart  = (int*)(h1q32 + (size_t)N_NODES * 16); // N_GRAPHS+1 (pad 516)
    float* Wc      = (float*)(gstart + 516);             // 64*5
    float* bc      = Wc + HIDDEN * N_CLASSES;            // 5

    const int BS = 256;
    const int g_nodes_sct = (N_NODES + SCT - 1) / SCT;   // 196 gstart blocks

    // zero gcur + all gsum replicas in one memset, then merged scatter kernel
    hipMemsetAsync(gcur, 0, (512 + NREP * N_GRAPHS * HIDDEN) * sizeof(int), stream);
    k_scat<<<EBLK + 1 + g_nodes_sct, SCT, 0, stream>>>(src, dst, W2, Wl, b2, bl, batch,
                                                       gcur, ebuf, Wc, bc, gstart);
    k_bktfill<<<N_BKT, 1024, 0, stream>>>(ebuf, gcur, x, rp, deg, dis, xs4, elist);

    // fused layer 1 (4 nodes/wave: 16-lane gather + W1 + local-pack quantize)
    k_l1fused<<<N_NODES / 16, BS, 0, stream>>>(rp, deg, elist, dis, xs4, W1, b1,
                                               h1q32, hscale);

    // layer 2 aggregation fused with mean-pool accumulation (1 node/wave,
    // 8 edges in flight — the round-5 experiment)
    k_gatherpool<<<N_NODES / 4, BS, 0, stream>>>(rp, deg, elist, dis,
                                                 (const unsigned char*)h1q32,
                                                 hscale, batch, gsum8);

    // folded head (block per graph; sums the NREP replicas)
    k_head<<<N_GRAPHS, HIDDEN, 0, stream>>>(gsum8, gstart, Wc, bc, out);
}

// Round 6
// 162.425 us; speedup vs baseline: 5.1999x; 1.0612x over previous
//
#include <hip/hip_runtime.h>
#include <hip/hip_bf16.h>

#define N_NODES   100000
#define N_EDGES   1250000
#define N_GRAPHS  512
#define HIDDEN    64
#define F_IN      3
#define N_CLASSES 5

// bucket sort parameters (legacy-proven: 161us)
#define BKT_SHIFT 8
#define BKT_NODES 256                                      // nodes per bucket
#define N_BKT     ((N_NODES + BKT_NODES - 1) / BKT_NODES)  // 391
#define CAP       4096                                     // fixed bucket capacity
#define EBLK      512                                      // edge blocks in k_scat
#define ECHUNK    ((N_EDGES + EBLK - 1) / EBLK)            // 2442
#define SCT       512                                      // k_scat threads
#define NREP      8                                        // gsum replicas

// bf16 helpers (RNE; inputs are finite)
__device__ __forceinline__ unsigned short f2bf(float f) {
    unsigned u = __float_as_uint(f);
    u += 0x7FFF + ((u >> 16) & 1);
    return (unsigned short)(u >> 16);
}

// ---------------------------------------------------------------------------
// k_scat: merged hist + bucket-base claim + scatter (+ head fold, gstart in
// extra blocks). Edges are cached in LDS during the hist pass, so src/dst are
// read from global exactly once. NO per-edge global atomics (R4: those cost
// ~107us in cross-XCD line bounce; per-block run claims avoid it).
__global__ void k_scat(const int* __restrict__ src, const int* __restrict__ dst,
                       const float* __restrict__ W2, const float* __restrict__ Wl,
                       const float* __restrict__ b2, const float* __restrict__ bl,
                       const int* __restrict__ batch,
                       int* __restrict__ gcur, int* __restrict__ ebuf,
                       float* __restrict__ Wc, float* __restrict__ bc,
                       int* __restrict__ gstart) {
    int b = blockIdx.x;
    int tid = threadIdx.x;
    if (b >= EBLK) {
        int bb = b - EBLK;
        if (bb == 0) {                      // head fold: Wc = W2@Wl, bc = b2@Wl+bl
            for (int t = tid; t < HIDDEN * N_CLASSES + N_CLASSES; t += SCT) {
                if (t < HIDDEN * N_CLASSES) {
                    int k = t / N_CLASSES, c = t % N_CLASSES;
                    float acc = 0.0f;
#pragma unroll
                    for (int j = 0; j < HIDDEN; j++)
                        acc = fmaf(W2[k * HIDDEN + j], Wl[j * N_CLASSES + c], acc);
                    Wc[t] = acc;
                } else {
                    int c = t - HIDDEN * N_CLASSES;
                    float acc = bl[c];
#pragma unroll
                    for (int j = 0; j < HIDDEN; j++)
                        acc = fmaf(b2[j], Wl[j * N_CLASSES + c], acc);
                    bc[c] = acc;
                }
            }
            return;
        }
        int n = (bb - 1) * SCT + tid;       // gstart from sorted batch
        if (n >= N_NODES) return;
        if (n == 0) {
            for (int g = 0; g <= batch[0]; g++) gstart[g] = 0;
        } else {
            int b0 = batch[n - 1], b1 = batch[n];
            for (int g = b0 + 1; g <= b1; g++) gstart[g] = n;
        }
        if (n == N_NODES - 1) {
            for (int g = batch[n] + 1; g <= N_GRAPHS; g++) gstart[g] = N_NODES;
        }
        return;
    }
    // scatter blocks: edges cached in LDS across the two passes
    __shared__ int pk[ECHUNK];
    __shared__ unsigned short bkl[ECHUNK];
    __shared__ int h[N_BKT];
    __shared__ int cur[N_BKT];
    for (int i = tid; i < N_BKT; i += SCT) h[i] = 0;
    __syncthreads();
    int e0 = b * ECHUNK;
    int m = min(ECHUNK, N_EDGES - e0);
    for (int i = tid; i < m; i += SCT) {
        int s = src[e0 + i], d = dst[e0 + i];
        int bk = d >> BKT_SHIFT;
        pk[i] = (s << BKT_SHIFT) | (d & (BKT_NODES - 1));
        bkl[i] = (unsigned short)bk;
        atomicAdd(&h[bk], 1);
    }
    __syncthreads();
    for (int i = tid; i < N_BKT; i += SCT)
        cur[i] = atomicAdd(&gcur[i], h[i]);    // claim this block's run in bucket i
    __syncthreads();
    for (int i = tid; i < m; i += SCT) {
        int bk = bkl[i];
        int lp = atomicAdd(&cur[bk], 1);
        if (lp < CAP)                           // defensive (P~0 overflow)
            ebuf[bk * CAP + lp] = pk[i];
    }
}

// k_bktfill: per-bucket CSR build, single global pass — the bucket's edges are
// cached in LDS (<=16KB) during the degree-hist pass, then the scatter reads
// from LDS. 391 blocks x 1024 threads.
__global__ void k_bktfill(const int* __restrict__ ebuf, const int* __restrict__ gcur,
                          const float* __restrict__ x,
                          int* __restrict__ rowptr, int* __restrict__ deg,
                          float* __restrict__ dis, uint2* __restrict__ xs4,
                          int* __restrict__ elist) {
    __shared__ int eb_l[CAP];
    __shared__ int cnt_l[BKT_NODES];
    __shared__ int cur_l[BKT_NODES];
    __shared__ int ps[BKT_NODES];
    int b = blockIdx.x, tid = threadIdx.x;   // 0..1023
    int n0 = b * BKT_NODES;
    int e0 = b * CAP;
    int cnt = min(gcur[b], CAP);
    if (tid < BKT_NODES) cnt_l[tid] = 0;
    __syncthreads();
    for (int i = tid; i < cnt; i += 1024) {
        int pe = ebuf[e0 + i];
        eb_l[i] = pe;
        atomicAdd(&cnt_l[pe & (BKT_NODES - 1)], 1);
    }
    __syncthreads();
    if (tid < BKT_NODES) ps[tid] = cnt_l[tid];
    __syncthreads();
    for (int off = 1; off < BKT_NODES; off <<= 1) {
        int t = 0;
        if (tid < BKT_NODES && tid >= off) t = ps[tid - off];
        __syncthreads();
        if (tid < BKT_NODES) ps[tid] += t;
        __syncthreads();
    }
    if (tid < BKT_NODES) {
        int node = n0 + tid;
        int excl = ps[tid] - cnt_l[tid];       // exclusive scan
        cur_l[tid] = excl;
        if (node < N_NODES) {
            rowptr[node] = e0 + excl;
            deg[node] = cnt_l[tid];
            float dv = rsqrtf((float)cnt_l[tid] + 1.0f);
            dis[node] = dv;
            float x0 = x[node * 3 + 0], x1 = x[node * 3 + 1], x2 = x[node * 3 + 2];
            xs4[node] = make_uint2((unsigned)f2bf(x0 * dv) |
                                   ((unsigned)f2bf(x1 * dv) << 16),
                                   (unsigned)f2bf(x2 * dv));
        }
    }
    __syncthreads();
    for (int i = tid; i < cnt; i += 1024) {
        int pe = eb_l[i];
        int pos = atomicAdd(&cur_l[pe & (BKT_NODES - 1)], 1);
        elist[e0 + pos] = ((unsigned)pe) >> BKT_SHIFT;
    }
}

// ---------------------------------------------------------------------------
// fused layer-1: FOUR nodes per wave (16 lanes each). Lane-parallel 3-channel
// gather, 4-stage quarter-butterfly, each lane computes 4 channels of
// relu(aggx@W1+b1)*dis.
// ROUND-6 CHANGE: store h1 as BF16 rows (128B/node, dis_src pre-multiplied)
// instead of int8 + per-row scale. Kills the rowmax butterfly + quantize in
// the epilogue here, and (the real target) kills the per-edge hscale gather
// + dequant chain in k_gatherpool.
__global__ void k_l1fused(const int* __restrict__ rp, const int* __restrict__ degA,
                          const int* __restrict__ elist,
                          const float* __restrict__ dis, const uint2* __restrict__ xs4,
                          const float* __restrict__ W1, const float* __restrict__ b1,
                          unsigned* __restrict__ h1b) {
    int w = threadIdx.x >> 6, lane = threadIdx.x & 63;
    int q4 = lane >> 4;                   // which of 4 nodes in this wave
    int j  = lane & 15;                   // lane within node (16-wide)
    int node = blockIdx.x * 16 + w * 4 + q4;   // 6250*16 = 100000 exact
    int start = rp[node], dg = degA[node];
    float a0 = 0.f, a1 = 0.f, a2 = 0.f;
    for (int k = 0; k < dg; k += 16) {    // divergent bound across quarters: ok
        int idx = k + j;
        bool act = idx < dg;
        int s = elist[start + (act ? idx : 0)];
        uint2 u = xs4[s];
        float msk = act ? 1.0f : 0.0f;
        a0 = fmaf(__uint_as_float(u.x << 16), msk, a0);
        a1 = fmaf(__uint_as_float(u.x & 0xFFFF0000u), msk, a1);
        a2 = fmaf(__uint_as_float(u.y << 16), msk, a2);
    }
#pragma unroll
    for (int off = 1; off < 16; off <<= 1) {   // butterfly within 16-lane quarter
        a0 += __shfl_xor(a0, off);
        a1 += __shfl_xor(a1, off);
        a2 += __shfl_xor(a2, off);
    }
    uint2 un = xs4[node];
    float dn = dis[node];
    a0 = dn * (a0 + __uint_as_float(un.x << 16));
    a1 = dn * (a1 + __uint_as_float(un.x & 0xFFFF0000u));
    a2 = dn * (a2 + __uint_as_float(un.y << 16));
    // each lane: channels 4j .. 4j+3; row element = relu(h1)*dis_node in bf16
    float v[4];
#pragma unroll
    for (int i = 0; i < 4; i++) {
        int c = 4 * j + i;
        float t = a0 * W1[c] + a1 * W1[HIDDEN + c] + a2 * W1[2 * HIDDEN + c] + b1[c];
        v[i] = fmaxf(t, 0.0f) * dn;
    }
    unsigned w0 = (unsigned)f2bf(v[0]) | ((unsigned)f2bf(v[1]) << 16);
    unsigned w1 = (unsigned)f2bf(v[2]) | ((unsigned)f2bf(v[3]) << 16);
    // row = 32 dwords; lane j owns dwords 2j,2j+1 -> 128B coalesced per node
    *(uint2*)(h1b + (size_t)node * 32 + j * 2) = make_uint2(w0, w1);
}

// ---------------------------------------------------------------------------
// fused 64-channel gather + mean-pool accumulate (legacy 2-node/wave geometry,
// R5's 1-node variant reverted). TWO nodes per wave (32 lanes each: 4 edges
// in flight x 8 uint4-slices of the 128B bf16 row).
// Inner loop: acc += row[src]  (no per-edge scale at all — row carries dis_src,
// and the dst-side dis_d is hoisted to the epilogue: out = dis_d*(sum+row[d])).
__global__ void k_gatherpool(const int* __restrict__ rp, const int* __restrict__ degA,
                             const int* __restrict__ elist,
                             const float* __restrict__ dis,
                             const unsigned* __restrict__ h1b,
                             const int* __restrict__ batch,
                             float* __restrict__ gsum8) {
    __shared__ float acc_s[8][HIDDEN];
    __shared__ int gid[8];
    int w = threadIdx.x >> 6, lane = threadIdx.x & 63;
    int half = lane >> 5;                       // which of 2 nodes in this wave
    int l32 = lane & 31;
    int node = blockIdx.x * 8 + w * 2 + half;   // 12500*8 = 100000 exact
    int start = rp[node], dg = degA[node];
    int eg = l32 >> 3;       // which of 4 concurrent edges
    int ch = lane & 7;       // which 16B slice (8 channels) of the 128B row
    float acc[8] = {0.f, 0.f, 0.f, 0.f, 0.f, 0.f, 0.f, 0.f};
    for (int k = 0; k < dg; k += 4) {     // divergent bound across halves: ok
        int idx = k + eg;
        bool act = idx < dg;
        int s = elist[start + (act ? idx : 0)];
        float msk = act ? 1.0f : 0.0f;
        uint4 u = *(const uint4*)(h1b + (size_t)s * 32 + ch * 4);
        acc[0] = fmaf(__uint_as_float(u.x << 16),          msk, acc[0]);
        acc[1] = fmaf(__uint_as_float(u.x & 0xFFFF0000u),  msk, acc[1]);
        acc[2] = fmaf(__uint_as_float(u.y << 16),          msk, acc[2]);
        acc[3] = fmaf(__uint_as_float(u.y & 0xFFFF0000u),  msk, acc[3]);
        acc[4] = fmaf(__uint_as_float(u.z << 16),          msk, acc[4]);
        acc[5] = fmaf(__uint_as_float(u.z & 0xFFFF0000u),  msk, acc[5]);
        acc[6] = fmaf(__uint_as_float(u.w << 16),          msk, acc[6]);
        acc[7] = fmaf(__uint_as_float(u.w & 0xFFFF0000u),  msk, acc[7]);
    }
#pragma unroll
    for (int i = 0; i < 8; i++) {         // reduce 4 edge-groups (within half)
        acc[i] += __shfl_xor(acc[i], 8);
        acc[i] += __shfl_xor(acc[i], 16);
    }
    if (l32 == 0) gid[w * 2 + half] = batch[node];
    if (l32 < 8) {                        // eg==0 lanes hold slice l32
        float dn = dis[node];
        uint4 u = *(const uint4*)(h1b + (size_t)node * 32 + l32 * 4);
        float o[8];
        o[0] = dn * (acc[0] + __uint_as_float(u.x << 16));
        o[1] = dn * (acc[1] + __uint_as_float(u.x & 0xFFFF0000u));
        o[2] = dn * (acc[2] + __uint_as_float(u.y << 16));
        o[3] = dn * (acc[3] + __uint_as_float(u.y & 0xFFFF0000u));
        o[4] = dn * (acc[4] + __uint_as_float(u.z << 16));
        o[5] = dn * (acc[5] + __uint_as_float(u.z & 0xFFFF0000u));
        o[6] = dn * (acc[6] + __uint_as_float(u.w << 16));
        o[7] = dn * (acc[7] + __uint_as_float(u.w & 0xFFFF0000u));
        float* dst = &acc_s[w * 2 + half][l32 * 8];
        *(float4*)(dst)     = make_float4(o[0], o[1], o[2], o[3]);
        *(float4*)(dst + 4) = make_float4(o[4], o[5], o[6], o[7]);
    }
    __syncthreads();
    float* gs = gsum8 + (size_t)(blockIdx.x & (NREP - 1)) * (N_GRAPHS * HIDDEN);
    if (threadIdx.x < HIDDEN) {
        int t = threadIdx.x;
#pragma unroll
        for (int wv = 0; wv < 8; wv++) {
            int gw = gid[wv];
            bool first = true;
#pragma unroll
            for (int u = 0; u < wv; u++)
                if (gid[u] == gw) first = false;
            if (first) {
                float s = acc_s[wv][t];
#pragma unroll
                for (int u2 = wv + 1; u2 < 8; u2++)
                    if (gid[u2] == gw) s += acc_s[u2][t];
                atomicAdd(&gs[gw * HIDDEN + t], s);
            }
        }
    }
}

// head: one block (64 thr) per graph; sum the NREP gsum replicas, then
// out[g,c] = (gl @ Wc[:,c]) / max(cnt,1) + bc[c]
__global__ void k_head(const float* __restrict__ gsum8, const int* __restrict__ gstart,
                       const float* __restrict__ Wc, const float* __restrict__ bc,
                       float* __restrict__ out) {
    __shared__ float gl[HIDDEN];
    int g = blockIdx.x, t = threadIdx.x;
    float s = 0.0f;
#pragma unroll
    for (int r = 0; r < NREP; r++)
        s += gsum8[(size_t)r * (N_GRAPHS * HIDDEN) + g * HIDDEN + t];
    gl[t] = s;
    __syncthreads();
    if (t < N_CLASSES) {
        float cntf = fmaxf((float)(gstart[g + 1] - gstart[g]), 1.0f);
        float dot = 0.0f;
#pragma unroll
        for (int k = 0; k < HIDDEN; k++)
            dot = fmaf(gl[k], Wc[k * N_CLASSES + t], dot);
        out[g * N_CLASSES + t] = dot / cntf + bc[t];
    }
}

// ---------------------------------------------------------------------------
extern "C" void kernel_launch(void* const* d_in, const int* in_sizes, int n_in,
                              void* d_out, int out_size, void* d_ws, size_t ws_size,
                              hipStream_t stream) {
    const float* x     = (const float*)d_in[0];
    const int*   ei    = (const int*)  d_in[1];   // [2, N_EDGES] flat: src then dst
    const int*   batch = (const int*)  d_in[2];
    const float* W1    = (const float*)d_in[3];
    const float* b1    = (const float*)d_in[4];
    const float* W2    = (const float*)d_in[5];
    const float* b2    = (const float*)d_in[6];
    const float* Wl    = (const float*)d_in[7];
    const float* bl    = (const float*)d_in[8];
    float* out = (float*)d_out;

    const int* src = ei;
    const int* dst = ei + N_EDGES;

    // workspace layout (4B words; gcur+gsum8 adjacent so ONE memset zeros both;
    // even word offsets keep xs4 8B- and h1b 16B-aligned)
    int*   gcur    = (int*)d_ws;                         // 391, pad to 512
    float* gsum8   = (float*)(gcur + 512);               // NREP*512*64
    int*   ebuf    = (int*)(gsum8 + NREP * N_GRAPHS * HIDDEN); // N_BKT*CAP
    int*   elist   = ebuf + N_BKT * CAP;                 // N_BKT*CAP
    int*   rp      = elist + N_BKT * CAP;                // N
    int*   deg     = rp + N_NODES;                       // N
    float* dis     = (float*)(deg + N_NODES);            // N
    uint2* xs4     = (uint2*)(dis + N_NODES);            // N uint2 (8B-aligned)
    unsigned* h1b  = (unsigned*)(xs4 + N_NODES);         // 32N words (bf16 rows)
    int*   gstart  = (int*)(h1b + (size_t)N_NODES * 32); // N_GRAPHS+1 (pad 516)
    float* Wc      = (float*)(gstart + 516);             // 64*5
    float* bc      = Wc + HIDDEN * N_CLASSES;            // 5

    const int BS = 256;
    const int g_nodes_sct = (N_NODES + SCT - 1) / SCT;   // 196 gstart blocks

    // zero gcur + all gsum replicas in one memset, then merged scatter kernel
    hipMemsetAsync(gcur, 0, (512 + NREP * N_GRAPHS * HIDDEN) * sizeof(int), stream);
    k_scat<<<EBLK + 1 + g_nodes_sct, SCT, 0, stream>>>(src, dst, W2, Wl, b2, bl, batch,
                                                       gcur, ebuf, Wc, bc, gstart);
    k_bktfill<<<N_BKT, 1024, 0, stream>>>(ebuf, gcur, x, rp, deg, dis, xs4, elist);

    // fused layer 1 (4 nodes/wave; bf16 128B row output)
    k_l1fused<<<N_NODES / 16, BS, 0, stream>>>(rp, deg, elist, dis, xs4, W1, b1,
                                               h1b);

    // layer 2 aggregation fused with mean-pool accumulation (2 nodes/wave,
    // bf16 rows: no per-edge scale gather)
    k_gatherpool<<<N_NODES / 8, BS, 0, stream>>>(rp, deg, elist, dis, h1b,
                                                 batch, gsum8);

    // folded head (block per graph; sums the NREP replicas)
    k_head<<<N_GRAPHS, HIDDEN, 0, stream>>>(gsum8, gstart, Wc, bc, out);
}

// Round 7
// 153.969 us; speedup vs baseline: 5.4855x; 1.0549x over previous
//
#include <hip/hip_runtime.h>
#include <hip/hip_bf16.h>

#define N_NODES   100000
#define N_EDGES   1250000
#define N_GRAPHS  512
#define HIDDEN    64
#define F_IN      3
#define N_CLASSES 5

// bucket sort parameters (legacy-proven: 161us)
#define BKT_SHIFT 8
#define BKT_NODES 256                                      // nodes per bucket
#define N_BKT     ((N_NODES + BKT_NODES - 1) / BKT_NODES)  // 391
#define CAP       4096                                     // fixed bucket capacity
#define EBLK      512                                      // edge blocks in k_scat
#define ECHUNK    ((N_EDGES + EBLK - 1) / EBLK)            // 2442
#define SCT       512                                      // k_scat threads
#define NREP      8                                        // gsum replicas

// bf16 helpers (RNE; inputs are finite)
__device__ __forceinline__ unsigned short f2bf(float f) {
    unsigned u = __float_as_uint(f);
    u += 0x7FFF + ((u >> 16) & 1);
    return (unsigned short)(u >> 16);
}

// ---------------------------------------------------------------------------
// k_scat: merged hist + bucket-base claim + scatter (+ head fold, gstart in
// extra blocks). Edges are cached in LDS during the hist pass, so src/dst are
// read from global exactly once. NO per-edge global atomics (R4: those cost
// ~107us in cross-XCD line bounce; per-block run claims avoid it).
__global__ void k_scat(const int* __restrict__ src, const int* __restrict__ dst,
                       const float* __restrict__ W2, const float* __restrict__ Wl,
                       const float* __restrict__ b2, const float* __restrict__ bl,
                       const int* __restrict__ batch,
                       int* __restrict__ gcur, int* __restrict__ ebuf,
                       float* __restrict__ Wc, float* __restrict__ bc,
                       int* __restrict__ gstart) {
    int b = blockIdx.x;
    int tid = threadIdx.x;
    if (b >= EBLK) {
        int bb = b - EBLK;
        if (bb == 0) {                      // head fold: Wc = W2@Wl, bc = b2@Wl+bl
            for (int t = tid; t < HIDDEN * N_CLASSES + N_CLASSES; t += SCT) {
                if (t < HIDDEN * N_CLASSES) {
                    int k = t / N_CLASSES, c = t % N_CLASSES;
                    float acc = 0.0f;
#pragma unroll
                    for (int j = 0; j < HIDDEN; j++)
                        acc = fmaf(W2[k * HIDDEN + j], Wl[j * N_CLASSES + c], acc);
                    Wc[t] = acc;
                } else {
                    int c = t - HIDDEN * N_CLASSES;
                    float acc = bl[c];
#pragma unroll
                    for (int j = 0; j < HIDDEN; j++)
                        acc = fmaf(b2[j], Wl[j * N_CLASSES + c], acc);
                    bc[c] = acc;
                }
            }
            return;
        }
        int n = (bb - 1) * SCT + tid;       // gstart from sorted batch
        if (n >= N_NODES) return;
        if (n == 0) {
            for (int g = 0; g <= batch[0]; g++) gstart[g] = 0;
        } else {
            int b0 = batch[n - 1], b1 = batch[n];
            for (int g = b0 + 1; g <= b1; g++) gstart[g] = n;
        }
        if (n == N_NODES - 1) {
            for (int g = batch[n] + 1; g <= N_GRAPHS; g++) gstart[g] = N_NODES;
        }
        return;
    }
    // scatter blocks: edges cached in LDS across the two passes
    __shared__ int pk[ECHUNK];
    __shared__ unsigned short bkl[ECHUNK];
    __shared__ int h[N_BKT];
    __shared__ int cur[N_BKT];
    for (int i = tid; i < N_BKT; i += SCT) h[i] = 0;
    __syncthreads();
    int e0 = b * ECHUNK;
    int m = min(ECHUNK, N_EDGES - e0);
    for (int i = tid; i < m; i += SCT) {
        int s = src[e0 + i], d = dst[e0 + i];
        int bk = d >> BKT_SHIFT;
        pk[i] = (s << BKT_SHIFT) | (d & (BKT_NODES - 1));
        bkl[i] = (unsigned short)bk;
        atomicAdd(&h[bk], 1);
    }
    __syncthreads();
    for (int i = tid; i < N_BKT; i += SCT)
        cur[i] = atomicAdd(&gcur[i], h[i]);    // claim this block's run in bucket i
    __syncthreads();
    for (int i = tid; i < m; i += SCT) {
        int bk = bkl[i];
        int lp = atomicAdd(&cur[bk], 1);
        if (lp < CAP)                           // defensive (P~0 overflow)
            ebuf[bk * CAP + lp] = pk[i];
    }
}

// k_bktfill: per-bucket CSR build, single global pass — the bucket's edges are
// cached in LDS (<=16KB) during the degree-hist pass, then the scatter reads
// from LDS. 391 blocks x 1024 threads.
__global__ void k_bktfill(const int* __restrict__ ebuf, const int* __restrict__ gcur,
                          const float* __restrict__ x,
                          int* __restrict__ rowptr, int* __restrict__ deg,
                          float* __restrict__ dis, uint2* __restrict__ xs4,
                          int* __restrict__ elist) {
    __shared__ int eb_l[CAP];
    __shared__ int cnt_l[BKT_NODES];
    __shared__ int cur_l[BKT_NODES];
    __shared__ int ps[BKT_NODES];
    int b = blockIdx.x, tid = threadIdx.x;   // 0..1023
    int n0 = b * BKT_NODES;
    int e0 = b * CAP;
    int cnt = min(gcur[b], CAP);
    if (tid < BKT_NODES) cnt_l[tid] = 0;
    __syncthreads();
    for (int i = tid; i < cnt; i += 1024) {
        int pe = ebuf[e0 + i];
        eb_l[i] = pe;
        atomicAdd(&cnt_l[pe & (BKT_NODES - 1)], 1);
    }
    __syncthreads();
    if (tid < BKT_NODES) ps[tid] = cnt_l[tid];
    __syncthreads();
    for (int off = 1; off < BKT_NODES; off <<= 1) {
        int t = 0;
        if (tid < BKT_NODES && tid >= off) t = ps[tid - off];
        __syncthreads();
        if (tid < BKT_NODES) ps[tid] += t;
        __syncthreads();
    }
    if (tid < BKT_NODES) {
        int node = n0 + tid;
        int excl = ps[tid] - cnt_l[tid];       // exclusive scan
        cur_l[tid] = excl;
        if (node < N_NODES) {
            rowptr[node] = e0 + excl;
            deg[node] = cnt_l[tid];
            float dv = rsqrtf((float)cnt_l[tid] + 1.0f);
            dis[node] = dv;
            float x0 = x[node * 3 + 0], x1 = x[node * 3 + 1], x2 = x[node * 3 + 2];
            xs4[node] = make_uint2((unsigned)f2bf(x0 * dv) |
                                   ((unsigned)f2bf(x1 * dv) << 16),
                                   (unsigned)f2bf(x2 * dv));
        }
    }
    __syncthreads();
    for (int i = tid; i < cnt; i += 1024) {
        int pe = eb_l[i];
        int pos = atomicAdd(&cur_l[pe & (BKT_NODES - 1)], 1);
        elist[e0 + pos] = ((unsigned)pe) >> BKT_SHIFT;
    }
}

// ---------------------------------------------------------------------------
// fused layer-1: FOUR nodes per wave (16 lanes each). Lane-parallel 3-channel
// gather, 4-stage quarter-butterfly, each lane computes 4 channels of
// relu(aggx@W1+b1)*dis, bf16 row output (128B/node, dis pre-multiplied).
// ROUND-7 CHANGE: gather loop unrolled x2 with both xs4 gathers issued before
// the fmas — doubles per-wave outstanding loads (G7 ILP; loop is latency-
// concurrency bound, compiler can't pipeline the runtime-bound gather chain).
__global__ void k_l1fused(const int* __restrict__ rp, const int* __restrict__ degA,
                          const int* __restrict__ elist,
                          const float* __restrict__ dis, const uint2* __restrict__ xs4,
                          const float* __restrict__ W1, const float* __restrict__ b1,
                          unsigned* __restrict__ h1b) {
    int w = threadIdx.x >> 6, lane = threadIdx.x & 63;
    int q4 = lane >> 4;                   // which of 4 nodes in this wave
    int j  = lane & 15;                   // lane within node (16-wide)
    int node = blockIdx.x * 16 + w * 4 + q4;   // 6250*16 = 100000 exact
    int start = rp[node], dg = degA[node];
    float a0 = 0.f, a1 = 0.f, a2 = 0.f;
    for (int k = 0; k < dg; k += 32) {    // 2 gathers in flight per lane
        int ia = k + j, ib = k + 16 + j;
        bool aa = ia < dg, ab = ib < dg;
        int sa = elist[start + (aa ? ia : 0)];
        int sb = elist[start + (ab ? ib : 0)];
        uint2 ua = xs4[sa];
        uint2 ub = xs4[sb];
        float ma = aa ? 1.0f : 0.0f;
        float mb = ab ? 1.0f : 0.0f;
        a0 = fmaf(__uint_as_float(ua.x << 16), ma, a0);
        a1 = fmaf(__uint_as_float(ua.x & 0xFFFF0000u), ma, a1);
        a2 = fmaf(__uint_as_float(ua.y << 16), ma, a2);
        a0 = fmaf(__uint_as_float(ub.x << 16), mb, a0);
        a1 = fmaf(__uint_as_float(ub.x & 0xFFFF0000u), mb, a1);
        a2 = fmaf(__uint_as_float(ub.y << 16), mb, a2);
    }
#pragma unroll
    for (int off = 1; off < 16; off <<= 1) {   // butterfly within 16-lane quarter
        a0 += __shfl_xor(a0, off);
        a1 += __shfl_xor(a1, off);
        a2 += __shfl_xor(a2, off);
    }
    uint2 un = xs4[node];
    float dn = dis[node];
    a0 = dn * (a0 + __uint_as_float(un.x << 16));
    a1 = dn * (a1 + __uint_as_float(un.x & 0xFFFF0000u));
    a2 = dn * (a2 + __uint_as_float(un.y << 16));
    // each lane: channels 4j .. 4j+3; row element = relu(h1)*dis_node in bf16
    float v[4];
#pragma unroll
    for (int i = 0; i < 4; i++) {
        int c = 4 * j + i;
        float t = a0 * W1[c] + a1 * W1[HIDDEN + c] + a2 * W1[2 * HIDDEN + c] + b1[c];
        v[i] = fmaxf(t, 0.0f) * dn;
    }
    unsigned w0 = (unsigned)f2bf(v[0]) | ((unsigned)f2bf(v[1]) << 16);
    unsigned w1 = (unsigned)f2bf(v[2]) | ((unsigned)f2bf(v[3]) << 16);
    // row = 32 dwords; lane j owns dwords 2j,2j+1 -> 128B coalesced per node
    *(uint2*)(h1b + (size_t)node * 32 + j * 2) = make_uint2(w0, w1);
}

// ---------------------------------------------------------------------------
// fused 64-channel gather + mean-pool accumulate (2 nodes/wave, bf16 rows).
// ROUND-7 CHANGE: inner loop unrolled x2 — two edges' 16B row slices issued
// back-to-back before either's fmas, doubling per-wave outstanding row loads
// (8 -> 16). Everything else identical to R6.
__global__ void k_gatherpool(const int* __restrict__ rp, const int* __restrict__ degA,
                             const int* __restrict__ elist,
                             const float* __restrict__ dis,
                             const unsigned* __restrict__ h1b,
                             const int* __restrict__ batch,
                             float* __restrict__ gsum8) {
    __shared__ float acc_s[8][HIDDEN];
    __shared__ int gid[8];
    int w = threadIdx.x >> 6, lane = threadIdx.x & 63;
    int half = lane >> 5;                       // which of 2 nodes in this wave
    int l32 = lane & 31;
    int node = blockIdx.x * 8 + w * 2 + half;   // 12500*8 = 100000 exact
    int start = rp[node], dg = degA[node];
    int eg = l32 >> 3;       // which of 4 concurrent edges
    int ch = lane & 7;       // which 16B slice (8 channels) of the 128B row
    float acc[8] = {0.f, 0.f, 0.f, 0.f, 0.f, 0.f, 0.f, 0.f};
    for (int k = 0; k < dg; k += 8) {     // 2 edges sequential per lane group
        int ia = k + eg;
        int ib = k + 4 + eg;
        bool aa = ia < dg, ab = ib < dg;
        int sa = elist[start + (aa ? ia : 0)];
        int sb = elist[start + (ab ? ib : 0)];
        float ma = aa ? 1.0f : 0.0f;
        float mb = ab ? 1.0f : 0.0f;
        uint4 ua = *(const uint4*)(h1b + (size_t)sa * 32 + ch * 4);
        uint4 ub = *(const uint4*)(h1b + (size_t)sb * 32 + ch * 4);
        acc[0] = fmaf(__uint_as_float(ua.x << 16),          ma, acc[0]);
        acc[1] = fmaf(__uint_as_float(ua.x & 0xFFFF0000u),  ma, acc[1]);
        acc[2] = fmaf(__uint_as_float(ua.y << 16),          ma, acc[2]);
        acc[3] = fmaf(__uint_as_float(ua.y & 0xFFFF0000u),  ma, acc[3]);
        acc[4] = fmaf(__uint_as_float(ua.z << 16),          ma, acc[4]);
        acc[5] = fmaf(__uint_as_float(ua.z & 0xFFFF0000u),  ma, acc[5]);
        acc[6] = fmaf(__uint_as_float(ua.w << 16),          ma, acc[6]);
        acc[7] = fmaf(__uint_as_float(ua.w & 0xFFFF0000u),  ma, acc[7]);
        acc[0] = fmaf(__uint_as_float(ub.x << 16),          mb, acc[0]);
        acc[1] = fmaf(__uint_as_float(ub.x & 0xFFFF0000u),  mb, acc[1]);
        acc[2] = fmaf(__uint_as_float(ub.y << 16),          mb, acc[2]);
        acc[3] = fmaf(__uint_as_float(ub.y & 0xFFFF0000u),  mb, acc[3]);
        acc[4] = fmaf(__uint_as_float(ub.z << 16),          mb, acc[4]);
        acc[5] = fmaf(__uint_as_float(ub.z & 0xFFFF0000u),  mb, acc[5]);
        acc[6] = fmaf(__uint_as_float(ub.w << 16),          mb, acc[6]);
        acc[7] = fmaf(__uint_as_float(ub.w & 0xFFFF0000u),  mb, acc[7]);
    }
#pragma unroll
    for (int i = 0; i < 8; i++) {         // reduce 4 edge-groups (within half)
        acc[i] += __shfl_xor(acc[i], 8);
        acc[i] += __shfl_xor(acc[i], 16);
    }
    if (l32 == 0) gid[w * 2 + half] = batch[node];
    if (l32 < 8) {                        // eg==0 lanes hold slice l32
        float dn = dis[node];
        uint4 u = *(const uint4*)(h1b + (size_t)node * 32 + l32 * 4);
        float o[8];
        o[0] = dn * (acc[0] + __uint_as_float(u.x << 16));
        o[1] = dn * (acc[1] + __uint_as_float(u.x & 0xFFFF0000u));
        o[2] = dn * (acc[2] + __uint_as_float(u.y << 16));
        o[3] = dn * (acc[3] + __uint_as_float(u.y & 0xFFFF0000u));
        o[4] = dn * (acc[4] + __uint_as_float(u.z << 16));
        o[5] = dn * (acc[5] + __uint_as_float(u.z & 0xFFFF0000u));
        o[6] = dn * (acc[6] + __uint_as_float(u.w << 16));
        o[7] = dn * (acc[7] + __uint_as_float(u.w & 0xFFFF0000u));
        float* dst = &acc_s[w * 2 + half][l32 * 8];
        *(float4*)(dst)     = make_float4(o[0], o[1], o[2], o[3]);
        *(float4*)(dst + 4) = make_float4(o[4], o[5], o[6], o[7]);
    }
    __syncthreads();
    float* gs = gsum8 + (size_t)(blockIdx.x & (NREP - 1)) * (N_GRAPHS * HIDDEN);
    if (threadIdx.x < HIDDEN) {
        int t = threadIdx.x;
#pragma unroll
        for (int wv = 0; wv < 8; wv++) {
            int gw = gid[wv];
            bool first = true;
#pragma unroll
            for (int u = 0; u < wv; u++)
                if (gid[u] == gw) first = false;
            if (first) {
                float s = acc_s[wv][t];
#pragma unroll
                for (int u2 = wv + 1; u2 < 8; u2++)
                    if (gid[u2] == gw) s += acc_s[u2][t];
                atomicAdd(&gs[gw * HIDDEN + t], s);
            }
        }
    }
}

// head: one block (64 thr) per graph; sum the NREP gsum replicas, then
// out[g,c] = (gl @ Wc[:,c]) / max(cnt,1) + bc[c]
__global__ void k_head(const float* __restrict__ gsum8, const int* __restrict__ gstart,
                       const float* __restrict__ Wc, const float* __restrict__ bc,
                       float* __restrict__ out) {
    __shared__ float gl[HIDDEN];
    int g = blockIdx.x, t = threadIdx.x;
    float s = 0.0f;
#pragma unroll
    for (int r = 0; r < NREP; r++)
        s += gsum8[(size_t)r * (N_GRAPHS * HIDDEN) + g * HIDDEN + t];
    gl[t] = s;
    __syncthreads();
    if (t < N_CLASSES) {
        float cntf = fmaxf((float)(gstart[g + 1] - gstart[g]), 1.0f);
        float dot = 0.0f;
#pragma unroll
        for (int k = 0; k < HIDDEN; k++)
            dot = fmaf(gl[k], Wc[k * N_CLASSES + t], dot);
        out[g * N_CLASSES + t] = dot / cntf + bc[t];
    }
}

// ---------------------------------------------------------------------------
extern "C" void kernel_launch(void* const* d_in, const int* in_sizes, int n_in,
                              void* d_out, int out_size, void* d_ws, size_t ws_size,
                              hipStream_t stream) {
    const float* x     = (const float*)d_in[0];
    const int*   ei    = (const int*)  d_in[1];   // [2, N_EDGES] flat: src then dst
    const int*   batch = (const int*)  d_in[2];
    const float* W1    = (const float*)d_in[3];
    const float* b1    = (const float*)d_in[4];
    const float* W2    = (const float*)d_in[5];
    const float* b2    = (const float*)d_in[6];
    const float* Wl    = (const float*)d_in[7];
    const float* bl    = (const float*)d_in[8];
    float* out = (float*)d_out;

    const int* src = ei;
    const int* dst = ei + N_EDGES;

    // workspace layout (4B words; gcur+gsum8 adjacent so ONE memset zeros both;
    // even word offsets keep xs4 8B- and h1b 16B-aligned)
    int*   gcur    = (int*)d_ws;                         // 391, pad to 512
    float* gsum8   = (float*)(gcur + 512);               // NREP*512*64
    int*   ebuf    = (int*)(gsum8 + NREP * N_GRAPHS * HIDDEN); // N_BKT*CAP
    int*   elist   = ebuf + N_BKT * CAP;                 // N_BKT*CAP
    int*   rp      = elist + N_BKT * CAP;                // N
    int*   deg     = rp + N_NODES;                       // N
    float* dis     = (float*)(deg + N_NODES);            // N
    uint2* xs4     = (uint2*)(dis + N_NODES);            // N uint2 (8B-aligned)
    unsigned* h1b  = (unsigned*)(xs4 + N_NODES);         // 32N words (bf16 rows)
    int*   gstart  = (int*)(h1b + (size_t)N_NODES * 32); // N_GRAPHS+1 (pad 516)
    float* Wc      = (float*)(gstart + 516);             // 64*5
    float* bc      = Wc + HIDDEN * N_CLASSES;            // 5

    const int BS = 256;
    const int g_nodes_sct = (N_NODES + SCT - 1) / SCT;   // 196 gstart blocks

    // zero gcur + all gsum replicas in one memset, then merged scatter kernel
    hipMemsetAsync(gcur, 0, (512 + NREP * N_GRAPHS * HIDDEN) * sizeof(int), stream);
    k_scat<<<EBLK + 1 + g_nodes_sct, SCT, 0, stream>>>(src, dst, W2, Wl, b2, bl, batch,
                                                       gcur, ebuf, Wc, bc, gstart);
    k_bktfill<<<N_BKT, 1024, 0, stream>>>(ebuf, gcur, x, rp, deg, dis, xs4, elist);

    // fused layer 1 (4 nodes/wave; 2 gathers in flight per lane)
    k_l1fused<<<N_NODES / 16, BS, 0, stream>>>(rp, deg, elist, dis, xs4, W1, b1,
                                               h1b);

    // layer 2 aggregation fused with mean-pool accumulation (2 nodes/wave,
    // 2 row loads in flight per lane)
    k_gatherpool<<<N_NODES / 8, BS, 0, stream>>>(rp, deg, elist, dis, h1b,
                                                 batch, gsum8);

    // folded head (block per graph; sums the NREP replicas)
    k_head<<<N_GRAPHS, HIDDEN, 0, stream>>>(gsum8, gstart, Wc, bc, out);
}

// Round 8
// 143.806 us; speedup vs baseline: 5.8731x; 1.0707x over previous
//
#include <hip/hip_runtime.h>
#include <hip/hip_bf16.h>

#define N_NODES   100000
#define N_EDGES   1250000
#define N_GRAPHS  512
#define HIDDEN    64
#define F_IN      3
#define N_CLASSES 5

// bucket sort parameters
#define BKT_SHIFT 8
#define BKT_NODES 256                                      // nodes per bucket
#define N_BKT     ((N_NODES + BKT_NODES - 1) / BKT_NODES)  // 391
#define CAP       4096                                     // fixed bucket capacity
#define EBLK      512                                      // edge blocks in k_scat
#define ECHUNK    ((N_EDGES + EBLK - 1) / EBLK)            // 2442
#define SCT       512                                      // k_scat threads
#define NREP      8                                        // gsum replicas

// bf16 helpers (RNE; inputs are finite)
__device__ __forceinline__ unsigned short f2bf(float f) {
    unsigned u = __float_as_uint(f);
    u += 0x7FFF + ((u >> 16) & 1);
    return (unsigned short)(u >> 16);
}

// ---------------------------------------------------------------------------
// k_scat: merged hist + scan + bucket-base claim + LDS counting-sort reorder
// + bucket-contiguous write-out (+ head fold, gstart in extra blocks).
// ROUND-8 CHANGE: edges are reordered by bucket IN LDS before the global
// write, so a wave's 64 stores form ~10 contiguous runs instead of 64
// scattered dwords (store-transaction reduction ~6x). Values and positions
// in ebuf are identical to R7's version (within-bucket order remains
// timing-dependent, as before).
__global__ void k_scat(const int* __restrict__ src, const int* __restrict__ dst,
                       const float* __restrict__ W2, const float* __restrict__ Wl,
                       const float* __restrict__ b2, const float* __restrict__ bl,
                       const int* __restrict__ batch,
                       int* __restrict__ gcur, int* __restrict__ ebuf,
                       float* __restrict__ Wc, float* __restrict__ bc,
                       int* __restrict__ gstart) {
    int b = blockIdx.x;
    int tid = threadIdx.x;
    if (b >= EBLK) {
        int bb = b - EBLK;
        if (bb == 0) {                      // head fold: Wc = W2@Wl, bc = b2@Wl+bl
            for (int t = tid; t < HIDDEN * N_CLASSES + N_CLASSES; t += SCT) {
                if (t < HIDDEN * N_CLASSES) {
                    int k = t / N_CLASSES, c = t % N_CLASSES;
                    float acc = 0.0f;
#pragma unroll
                    for (int j = 0; j < HIDDEN; j++)
                        acc = fmaf(W2[k * HIDDEN + j], Wl[j * N_CLASSES + c], acc);
                    Wc[t] = acc;
                } else {
                    int c = t - HIDDEN * N_CLASSES;
                    float acc = bl[c];
#pragma unroll
                    for (int j = 0; j < HIDDEN; j++)
                        acc = fmaf(b2[j], Wl[j * N_CLASSES + c], acc);
                    bc[c] = acc;
                }
            }
            return;
        }
        int n = (bb - 1) * SCT + tid;       // gstart from sorted batch
        if (n >= N_NODES) return;
        if (n == 0) {
            for (int g = 0; g <= batch[0]; g++) gstart[g] = 0;
        } else {
            int b0 = batch[n - 1], b1 = batch[n];
            for (int g = b0 + 1; g <= b1; g++) gstart[g] = n;
        }
        if (n == N_NODES - 1) {
            for (int g = batch[n] + 1; g <= N_GRAPHS; g++) gstart[g] = N_NODES;
        }
        return;
    }
    // scatter blocks
    __shared__ int pk[ECHUNK];
    __shared__ unsigned short bkl[ECHUNK];
    __shared__ int spk[ECHUNK];             // bucket-sorted pk
    __shared__ unsigned short sbk[ECHUNK];  // bucket id of sorted slot
    __shared__ int h[N_BKT];                // per-bucket count
    __shared__ int lsc[N_BKT];              // inclusive local scan
    __shared__ int gb[N_BKT];               // claimed global base
    __shared__ int cur[N_BKT];              // local running cursor
    for (int i = tid; i < N_BKT; i += SCT) h[i] = 0;
    __syncthreads();
    int e0 = b * ECHUNK;
    int m = min(ECHUNK, N_EDGES - e0);
    for (int i = tid; i < m; i += SCT) {
        int s = src[e0 + i], d = dst[e0 + i];
        int bk = d >> BKT_SHIFT;
        pk[i] = (s << BKT_SHIFT) | (d & (BKT_NODES - 1));
        bkl[i] = (unsigned short)bk;
        atomicAdd(&h[bk], 1);
    }
    __syncthreads();
    if (tid < N_BKT) lsc[tid] = h[tid];     // N_BKT=391 < SCT
    __syncthreads();
    for (int off = 1; off < N_BKT; off <<= 1) {   // Hillis-Steele inclusive
        int t = 0;
        if (tid < N_BKT && tid >= off) t = lsc[tid - off];
        __syncthreads();
        if (tid < N_BKT) lsc[tid] += t;
        __syncthreads();
    }
    if (tid < N_BKT) {
        gb[tid] = atomicAdd(&gcur[tid], h[tid]);  // claim this block's runs
        cur[tid] = lsc[tid] - h[tid];             // local exclusive base
    }
    __syncthreads();
    for (int i = tid; i < m; i += SCT) {          // LDS counting-sort reorder
        int bk = bkl[i];
        int p = atomicAdd(&cur[bk], 1);
        spk[p] = pk[i];
        sbk[p] = (unsigned short)bk;
    }
    __syncthreads();
    for (int i = tid; i < m; i += SCT) {          // bucket-contiguous write-out
        int bk = sbk[i];
        int gpos = gb[bk] + (i - (lsc[bk] - h[bk]));
        if (gpos < CAP)                            // defensive (P~0 overflow)
            ebuf[bk * CAP + gpos] = spk[i];
    }
}

// k_bktfill: per-bucket CSR build, single global pass.
// ROUND-8 CHANGE: final elist scatter goes through an LDS sorted buffer
// (the node-order positions are already given by the ps scan), then a fully
// coalesced copy-out — removes 1.25M scattered 4B global stores.
__global__ void k_bktfill(const int* __restrict__ ebuf, const int* __restrict__ gcur,
                          const float* __restrict__ x,
                          int* __restrict__ rowptr, int* __restrict__ deg,
                          float* __restrict__ dis, uint2* __restrict__ xs4,
                          int* __restrict__ elist) {
    __shared__ int eb_l[CAP];
    __shared__ int sorted_l[CAP];
    __shared__ int cnt_l[BKT_NODES];
    __shared__ int cur_l[BKT_NODES];
    __shared__ int ps[BKT_NODES];
    int b = blockIdx.x, tid = threadIdx.x;   // 0..1023
    int n0 = b * BKT_NODES;
    int e0 = b * CAP;
    int cnt = min(gcur[b], CAP);
    if (tid < BKT_NODES) cnt_l[tid] = 0;
    __syncthreads();
    for (int i = tid; i < cnt; i += 1024) {
        int pe = ebuf[e0 + i];
        eb_l[i] = pe;
        atomicAdd(&cnt_l[pe & (BKT_NODES - 1)], 1);
    }
    __syncthreads();
    if (tid < BKT_NODES) ps[tid] = cnt_l[tid];
    __syncthreads();
    for (int off = 1; off < BKT_NODES; off <<= 1) {
        int t = 0;
        if (tid < BKT_NODES && tid >= off) t = ps[tid - off];
        __syncthreads();
        if (tid < BKT_NODES) ps[tid] += t;
        __syncthreads();
    }
    if (tid < BKT_NODES) {
        int node = n0 + tid;
        int excl = ps[tid] - cnt_l[tid];       // exclusive scan
        cur_l[tid] = excl;
        if (node < N_NODES) {
            rowptr[node] = e0 + excl;
            deg[node] = cnt_l[tid];
            float dv = rsqrtf((float)cnt_l[tid] + 1.0f);
            dis[node] = dv;
            float x0 = x[node * 3 + 0], x1 = x[node * 3 + 1], x2 = x[node * 3 + 2];
            xs4[node] = make_uint2((unsigned)f2bf(x0 * dv) |
                                   ((unsigned)f2bf(x1 * dv) << 16),
                                   (unsigned)f2bf(x2 * dv));
        }
    }
    __syncthreads();
    for (int i = tid; i < cnt; i += 1024) {    // scatter in LDS (node order)
        int pe = eb_l[i];
        int pos = atomicAdd(&cur_l[pe & (BKT_NODES - 1)], 1);
        sorted_l[pos] = ((unsigned)pe) >> BKT_SHIFT;
    }
    __syncthreads();
    for (int i = tid; i < cnt; i += 1024)      // coalesced copy-out
        elist[e0 + i] = sorted_l[i];
}

// ---------------------------------------------------------------------------
// fused layer-1: FOUR nodes per wave (16 lanes each), 2 gathers in flight per
// lane (R7-proven), bf16 row output (128B/node, dis pre-multiplied).
__global__ void k_l1fused(const int* __restrict__ rp, const int* __restrict__ degA,
                          const int* __restrict__ elist,
                          const float* __restrict__ dis, const uint2* __restrict__ xs4,
                          const float* __restrict__ W1, const float* __restrict__ b1,
                          unsigned* __restrict__ h1b) {
    int w = threadIdx.x >> 6, lane = threadIdx.x & 63;
    int q4 = lane >> 4;                   // which of 4 nodes in this wave
    int j  = lane & 15;                   // lane within node (16-wide)
    int node = blockIdx.x * 16 + w * 4 + q4;   // 6250*16 = 100000 exact
    int start = rp[node], dg = degA[node];
    float a0 = 0.f, a1 = 0.f, a2 = 0.f;
    for (int k = 0; k < dg; k += 32) {    // 2 gathers in flight per lane
        int ia = k + j, ib = k + 16 + j;
        bool aa = ia < dg, ab = ib < dg;
        int sa = elist[start + (aa ? ia : 0)];
        int sb = elist[start + (ab ? ib : 0)];
        uint2 ua = xs4[sa];
        uint2 ub = xs4[sb];
        float ma = aa ? 1.0f : 0.0f;
        float mb = ab ? 1.0f : 0.0f;
        a0 = fmaf(__uint_as_float(ua.x << 16), ma, a0);
        a1 = fmaf(__uint_as_float(ua.x & 0xFFFF0000u), ma, a1);
        a2 = fmaf(__uint_as_float(ua.y << 16), ma, a2);
        a0 = fmaf(__uint_as_float(ub.x << 16), mb, a0);
        a1 = fmaf(__uint_as_float(ub.x & 0xFFFF0000u), mb, a1);
        a2 = fmaf(__uint_as_float(ub.y << 16), mb, a2);
    }
#pragma unroll
    for (int off = 1; off < 16; off <<= 1) {   // butterfly within 16-lane quarter
        a0 += __shfl_xor(a0, off);
        a1 += __shfl_xor(a1, off);
        a2 += __shfl_xor(a2, off);
    }
    uint2 un = xs4[node];
    float dn = dis[node];
    a0 = dn * (a0 + __uint_as_float(un.x << 16));
    a1 = dn * (a1 + __uint_as_float(un.x & 0xFFFF0000u));
    a2 = dn * (a2 + __uint_as_float(un.y << 16));
    // each lane: channels 4j .. 4j+3; row element = relu(h1)*dis_node in bf16
    float v[4];
#pragma unroll
    for (int i = 0; i < 4; i++) {
        int c = 4 * j + i;
        float t = a0 * W1[c] + a1 * W1[HIDDEN + c] + a2 * W1[2 * HIDDEN + c] + b1[c];
        v[i] = fmaxf(t, 0.0f) * dn;
    }
    unsigned w0 = (unsigned)f2bf(v[0]) | ((unsigned)f2bf(v[1]) << 16);
    unsigned w1 = (unsigned)f2bf(v[2]) | ((unsigned)f2bf(v[3]) << 16);
    // row = 32 dwords; lane j owns dwords 2j,2j+1 -> 128B coalesced per node
    *(uint2*)(h1b + (size_t)node * 32 + j * 2) = make_uint2(w0, w1);
}

// ---------------------------------------------------------------------------
// fused 64-channel gather + mean-pool accumulate (2 nodes/wave, bf16 rows).
// ROUND-8 CHANGE: inner loop unrolled x4 (was x2) — four edges' 16B row
// slices issued back-to-back before any fmas; 32 outstanding row loads per
// wave. Mean deg 12.5 -> typically a single iteration.
__global__ void k_gatherpool(const int* __restrict__ rp, const int* __restrict__ degA,
                             const int* __restrict__ elist,
                             const float* __restrict__ dis,
                             const unsigned* __restrict__ h1b,
                             const int* __restrict__ batch,
                             float* __restrict__ gsum8) {
    __shared__ float acc_s[8][HIDDEN];
    __shared__ int gid[8];
    int w = threadIdx.x >> 6, lane = threadIdx.x & 63;
    int half = lane >> 5;                       // which of 2 nodes in this wave
    int l32 = lane & 31;
    int node = blockIdx.x * 8 + w * 2 + half;   // 12500*8 = 100000 exact
    int start = rp[node], dg = degA[node];
    int eg = l32 >> 3;       // which of 4 concurrent edges
    int ch = lane & 7;       // which 16B slice (8 channels) of the 128B row
    float acc[8] = {0.f, 0.f, 0.f, 0.f, 0.f, 0.f, 0.f, 0.f};
    for (int k = 0; k < dg; k += 16) {    // 4 edges sequential per lane group
        int i0 = k + eg, i1 = k + 4 + eg, i2 = k + 8 + eg, i3 = k + 12 + eg;
        bool a0b = i0 < dg, a1b = i1 < dg, a2b = i2 < dg, a3b = i3 < dg;
        int s0 = elist[start + (a0b ? i0 : 0)];
        int s1 = elist[start + (a1b ? i1 : 0)];
        int s2 = elist[start + (a2b ? i2 : 0)];
        int s3 = elist[start + (a3b ? i3 : 0)];
        float m0 = a0b ? 1.0f : 0.0f;
        float m1 = a1b ? 1.0f : 0.0f;
        float m2 = a2b ? 1.0f : 0.0f;
        float m3 = a3b ? 1.0f : 0.0f;
        uint4 u0 = *(const uint4*)(h1b + (size_t)s0 * 32 + ch * 4);
        uint4 u1 = *(const uint4*)(h1b + (size_t)s1 * 32 + ch * 4);
        uint4 u2 = *(const uint4*)(h1b + (size_t)s2 * 32 + ch * 4);
        uint4 u3 = *(const uint4*)(h1b + (size_t)s3 * 32 + ch * 4);
        acc[0] = fmaf(__uint_as_float(u0.x << 16),          m0, acc[0]);
        acc[1] = fmaf(__uint_as_float(u0.x & 0xFFFF0000u),  m0, acc[1]);
        acc[2] = fmaf(__uint_as_float(u0.y << 16),          m0, acc[2]);
        acc[3] = fmaf(__uint_as_float(u0.y & 0xFFFF0000u),  m0, acc[3]);
        acc[4] = fmaf(__uint_as_float(u0.z << 16),          m0, acc[4]);
        acc[5] = fmaf(__uint_as_float(u0.z & 0xFFFF0000u),  m0, acc[5]);
        acc[6] = fmaf(__uint_as_float(u0.w << 16),          m0, acc[6]);
        acc[7] = fmaf(__uint_as_float(u0.w & 0xFFFF0000u),  m0, acc[7]);
        acc[0] = fmaf(__uint_as_float(u1.x << 16),          m1, acc[0]);
        acc[1] = fmaf(__uint_as_float(u1.x & 0xFFFF0000u),  m1, acc[1]);
        acc[2] = fmaf(__uint_as_float(u1.y << 16),          m1, acc[2]);
        acc[3] = fmaf(__uint_as_float(u1.y & 0xFFFF0000u),  m1, acc[3]);
        acc[4] = fmaf(__uint_as_float(u1.z << 16),          m1, acc[4]);
        acc[5] = fmaf(__uint_as_float(u1.z & 0xFFFF0000u),  m1, acc[5]);
        acc[6] = fmaf(__uint_as_float(u1.w << 16),          m1, acc[6]);
        acc[7] = fmaf(__uint_as_float(u1.w & 0xFFFF0000u),  m1, acc[7]);
        acc[0] = fmaf(__uint_as_float(u2.x << 16),          m2, acc[0]);
        acc[1] = fmaf(__uint_as_float(u2.x & 0xFFFF0000u),  m2, acc[1]);
        acc[2] = fmaf(__uint_as_float(u2.y << 16),          m2, acc[2]);
        acc[3] = fmaf(__uint_as_float(u2.y & 0xFFFF0000u),  m2, acc[3]);
        acc[4] = fmaf(__uint_as_float(u2.z << 16),          m2, acc[4]);
        acc[5] = fmaf(__uint_as_float(u2.z & 0xFFFF0000u),  m2, acc[5]);
        acc[6] = fmaf(__uint_as_float(u2.w << 16),          m2, acc[6]);
        acc[7] = fmaf(__uint_as_float(u2.w & 0xFFFF0000u),  m2, acc[7]);
        acc[0] = fmaf(__uint_as_float(u3.x << 16),          m3, acc[0]);
        acc[1] = fmaf(__uint_as_float(u3.x & 0xFFFF0000u),  m3, acc[1]);
        acc[2] = fmaf(__uint_as_float(u3.y << 16),          m3, acc[2]);
        acc[3] = fmaf(__uint_as_float(u3.y & 0xFFFF0000u),  m3, acc[3]);
        acc[4] = fmaf(__uint_as_float(u3.z << 16),          m3, acc[4]);
        acc[5] = fmaf(__uint_as_float(u3.z & 0xFFFF0000u),  m3, acc[5]);
        acc[6] = fmaf(__uint_as_float(u3.w << 16),          m3, acc[6]);
        acc[7] = fmaf(__uint_as_float(u3.w & 0xFFFF0000u),  m3, acc[7]);
    }
#pragma unroll
    for (int i = 0; i < 8; i++) {         // reduce 4 edge-groups (within half)
        acc[i] += __shfl_xor(acc[i], 8);
        acc[i] += __shfl_xor(acc[i], 16);
    }
    if (l32 == 0) gid[w * 2 + half] = batch[node];
    if (l32 < 8) {                        // eg==0 lanes hold slice l32
        float dn = dis[node];
        uint4 u = *(const uint4*)(h1b + (size_t)node * 32 + l32 * 4);
        float o[8];
        o[0] = dn * (acc[0] + __uint_as_float(u.x << 16));
        o[1] = dn * (acc[1] + __uint_as_float(u.x & 0xFFFF0000u));
        o[2] = dn * (acc[2] + __uint_as_float(u.y << 16));
        o[3] = dn * (acc[3] + __uint_as_float(u.y & 0xFFFF0000u));
        o[4] = dn * (acc[4] + __uint_as_float(u.z << 16));
        o[5] = dn * (acc[5] + __uint_as_float(u.z & 0xFFFF0000u));
        o[6] = dn * (acc[6] + __uint_as_float(u.w << 16));
        o[7] = dn * (acc[7] + __uint_as_float(u.w & 0xFFFF0000u));
        float* dst = &acc_s[w * 2 + half][l32 * 8];
        *(float4*)(dst)     = make_float4(o[0], o[1], o[2], o[3]);
        *(float4*)(dst + 4) = make_float4(o[4], o[5], o[6], o[7]);
    }
    __syncthreads();
    float* gs = gsum8 + (size_t)(blockIdx.x & (NREP - 1)) * (N_GRAPHS * HIDDEN);
    if (threadIdx.x < HIDDEN) {
        int t = threadIdx.x;
#pragma unroll
        for (int wv = 0; wv < 8; wv++) {
            int gw = gid[wv];
            bool first = true;
#pragma unroll
            for (int u = 0; u < wv; u++)
                if (gid[u] == gw) first = false;
            if (first) {
                float s = acc_s[wv][t];
#pragma unroll
                for (int u2 = wv + 1; u2 < 8; u2++)
                    if (gid[u2] == gw) s += acc_s[u2][t];
                atomicAdd(&gs[gw * HIDDEN + t], s);
            }
        }
    }
}

// head: one block (64 thr) per graph; sum the NREP gsum replicas, then
// out[g,c] = (gl @ Wc[:,c]) / max(cnt,1) + bc[c]
__global__ void k_head(const float* __restrict__ gsum8, const int* __restrict__ gstart,
                       const float* __restrict__ Wc, const float* __restrict__ bc,
                       float* __restrict__ out) {
    __shared__ float gl[HIDDEN];
    int g = blockIdx.x, t = threadIdx.x;
    float s = 0.0f;
#pragma unroll
    for (int r = 0; r < NREP; r++)
        s += gsum8[(size_t)r * (N_GRAPHS * HIDDEN) + g * HIDDEN + t];
    gl[t] = s;
    __syncthreads();
    if (t < N_CLASSES) {
        float cntf = fmaxf((float)(gstart[g + 1] - gstart[g]), 1.0f);
        float dot = 0.0f;
#pragma unroll
        for (int k = 0; k < HIDDEN; k++)
            dot = fmaf(gl[k], Wc[k * N_CLASSES + t], dot);
        out[g * N_CLASSES + t] = dot / cntf + bc[t];
    }
}

// ---------------------------------------------------------------------------
extern "C" void kernel_launch(void* const* d_in, const int* in_sizes, int n_in,
                              void* d_out, int out_size, void* d_ws, size_t ws_size,
                              hipStream_t stream) {
    const float* x     = (const float*)d_in[0];
    const int*   ei    = (const int*)  d_in[1];   // [2, N_EDGES] flat: src then dst
    const int*   batch = (const int*)  d_in[2];
    const float* W1    = (const float*)d_in[3];
    const float* b1    = (const float*)d_in[4];
    const float* W2    = (const float*)d_in[5];
    const float* b2    = (const float*)d_in[6];
    const float* Wl    = (const float*)d_in[7];
    const float* bl    = (const float*)d_in[8];
    float* out = (float*)d_out;

    const int* src = ei;
    const int* dst = ei + N_EDGES;

    // workspace layout (4B words; gcur+gsum8 adjacent so ONE memset zeros both;
    // even word offsets keep xs4 8B- and h1b 16B-aligned)
    int*   gcur    = (int*)d_ws;                         // 391, pad to 512
    float* gsum8   = (float*)(gcur + 512);               // NREP*512*64
    int*   ebuf    = (int*)(gsum8 + NREP * N_GRAPHS * HIDDEN); // N_BKT*CAP
    int*   elist   = ebuf + N_BKT * CAP;                 // N_BKT*CAP
    int*   rp      = elist + N_BKT * CAP;                // N
    int*   deg     = rp + N_NODES;                       // N
    float* dis     = (float*)(deg + N_NODES);            // N
    uint2* xs4     = (uint2*)(dis + N_NODES);            // N uint2 (8B-aligned)
    unsigned* h1b  = (unsigned*)(xs4 + N_NODES);         // 32N words (bf16 rows)
    int*   gstart  = (int*)(h1b + (size_t)N_NODES * 32); // N_GRAPHS+1 (pad 516)
    float* Wc      = (float*)(gstart + 516);             // 64*5
    float* bc      = Wc + HIDDEN * N_CLASSES;            // 5

    const int BS = 256;
    const int g_nodes_sct = (N_NODES + SCT - 1) / SCT;   // 196 gstart blocks

    // zero gcur + all gsum replicas in one memset, then merged scatter kernel
    hipMemsetAsync(gcur, 0, (512 + NREP * N_GRAPHS * HIDDEN) * sizeof(int), stream);
    k_scat<<<EBLK + 1 + g_nodes_sct, SCT, 0, stream>>>(src, dst, W2, Wl, b2, bl, batch,
                                                       gcur, ebuf, Wc, bc, gstart);
    k_bktfill<<<N_BKT, 1024, 0, stream>>>(ebuf, gcur, x, rp, deg, dis, xs4, elist);

    // fused layer 1 (4 nodes/wave; 2 gathers in flight per lane)
    k_l1fused<<<N_NODES / 16, BS, 0, stream>>>(rp, deg, elist, dis, xs4, W1, b1,
                                               h1b);

    // layer 2 aggregation fused with mean-pool accumulation (2 nodes/wave,
    // 4 row loads in flight per lane)
    k_gatherpool<<<N_NODES / 8, BS, 0, stream>>>(rp, deg, elist, dis, h1b,
                                                 batch, gsum8);

    // folded head (block per graph; sums the NREP replicas)
    k_head<<<N_GRAPHS, HIDDEN, 0, stream>>>(gsum8, gstart, Wc, bc, out);
}